// Round 18
// baseline (669.223 us; speedup 1.0000x reference)
//
#include <hip/hip_runtime.h>
#include <math.h>

// ---------------------------------------------------------------------------
// E3NN conv: N=10000 nodes, E=128000 edges, MUL=12, B=10 rbf, H=32 hidden.
// 15 combos (i,f,o). Outputs: o0 (N,12), o1 (N,36), o2 (N,60) concat flat.
//
// Round 18: resubmission of the round-15 kernel verbatim — the fastest fully
// verified configuration (663us, passes first + post-timing validation).
// The r16/r17 two-tile pipeline corrupted outputs in ways desk-checking could
// not localize (pattern: extreme VGPR pressure + inline-asm fences); it is
// abandoned. This kernel carries every verified win:
//   r3  CSR gather (scatter -> gather, LDS accumulate)
//   r6/r9 lgkm-only fences (no vmcnt drain) + in-place prefetch pipeline
//   r7  swapped-operand MFMA (lane owns its edge's Wr row, b128 staging)
//   r11/r13 rW2 fragments + rW1/rb1 hoisted to registers
//   r12 esort'd linear edge streams (eattr4 + padded xi q-slices)
//   r13 dst-segmented shuffle scan (one LDS atomic per dst-run)
//   r15 wave-per-node out_kernel (coalesced staging) + vectorized ins_kernel
// ---------------------------------------------------------------------------

#define NCOMB 15
#define DG 16          // dsts per block
#define GT 64          // gather block threads (1 wave)

// LDS visibility fence for single-wave LDS slices: no s_barrier, no vmcnt drain.
#define LDS_FENCE() do { \
    asm volatile("s_waitcnt lgkmcnt(0)" ::: "memory"); \
    __builtin_amdgcn_sched_barrier(0); \
} while (0)

typedef float f32x4 __attribute__((ext_vector_type(4)));
typedef short bf16x8 __attribute__((ext_vector_type(8)));

constexpr int kCGOFF[NCOMB] = {0,1,10,35,44,53,80,125,170,245,270,315,390,415,490};

__device__ const int dCI[NCOMB]    = {0,0,0,1,1,1,1,1,1,2,2,2,2,2,2};
__device__ const int dCF[NCOMB]    = {0,1,2,0,1,1,1,2,2,0,1,1,2,2,2};
__device__ const int dCO[NCOMB]    = {0,1,2,1,0,1,2,1,2,2,1,2,0,1,2};
__device__ const int dCGOFF[NCOMB] = {0,1,10,35,44,53,80,125,170,245,270,315,390,415,490};
// heavy combos (O2=5, big I2*F2) first -> short scheduling tail
__device__ const int dCORDER[NCOMB] = {14,8,11,2,9,6,13,7,10,5,12,3,1,4,0};

// bf16 round-to-nearest-even helpers
__device__ __forceinline__ unsigned short bfhi(float f) {
    unsigned u = __float_as_uint(f);
    return (unsigned short)((u + 0x7FFFu + ((u >> 16) & 1u)) >> 16);
}
__device__ __forceinline__ float bff(unsigned short h) {
    return __uint_as_float(((unsigned)h) << 16);
}

// ---------------------------------------------------------------------------
// CG setup (bit-matches numpy: contract-off, numpy's r2, lexicographic order)
// ---------------------------------------------------------------------------
__device__ inline double dfact(int n) {
    double r = 1.0;
    for (int k = 2; k <= n; ++k) r *= (double)k;
    return r;
}

__device__ double su2cg(int j1, int j2, int j3, int m1, int m2, int m3) {
#pragma clang fp contract(off)
    if (m1 + m2 != m3) return 0.0;
    double pref = sqrt((2.0 * j3 + 1.0) * dfact(j3 + j1 - j2) * dfact(j3 - j1 + j2) *
                       dfact(j1 + j2 - j3) / dfact(j1 + j2 + j3 + 1));
    pref *= sqrt(dfact(j3 + m3) * dfact(j3 - m3) * dfact(j1 - m1) * dfact(j1 + m1) *
                 dfact(j2 - m2) * dfact(j2 + m2));
    int k0 = 0;
    if (j2 - j3 - m1 > k0) k0 = j2 - j3 - m1;
    if (j1 - j3 + m2 > k0) k0 = j1 - j3 + m2;
    int k1 = j1 + j2 - j3;
    if (j1 - m1 < k1) k1 = j1 - m1;
    if (j2 + m2 < k1) k1 = j2 + m2;
    double s = 0.0;
    for (int k = k0; k <= k1; ++k) {
        double t = 1.0 / (dfact(k) * dfact(j1 + j2 - j3 - k) * dfact(j1 - m1 - k) *
                          dfact(j2 + m2 - k) * dfact(j3 - j2 + m1 + k) * dfact(j3 - j1 - m2 + k));
        s += (k & 1) ? -t : t;
    }
    return pref * s;
}

__device__ inline void qval(int l, int r, int c, double& re, double& im) {
#pragma clang fp contract(off)
    re = 0.0; im = 0.0;
    const double r2 = __longlong_as_double(0x3FE6A09E667F3BCCLL);  // numpy 1/sqrt(2)
    int m = r - l;
    if (m == 0) { if (c == l) re = 1.0; return; }
    if (m < 0) {
        if (c == r) im = -r2;
        else if (c == 2 * l - r) re = r2;
    } else {
        double sg = (m & 1) ? -1.0 : 1.0;
        if (c == r) re = sg * r2;
        else if (c == 2 * l - r) im = sg * r2;
    }
}

__global__ void cg_setup(float* __restrict__ out) {
#pragma clang fp contract(off)
    int c = blockIdx.x;
    if (c >= NCOMB) return;
    const int i = dCI[c], f = dCF[c], o = dCO[c];
    const int I2 = 2 * i + 1, F2 = 2 * f + 1, O2 = 2 * o + 1;
    const int sz = I2 * F2 * O2;
    const int t = threadIdx.x;

    double re = 0.0, im = 0.0;
    if (t < sz) {
        int a = t / (F2 * O2);
        int rem = t % (F2 * O2);
        int b = rem / O2;
        int cc = rem % O2;
        for (int ii = 0; ii < I2; ++ii) {
            double a1r, a1i; qval(i, a, ii, a1r, a1i);
            if (a1r == 0.0 && a1i == 0.0) continue;
            for (int jj = 0; jj < F2; ++jj) {
                double a2r, a2i; qval(f, b, jj, a2r, a2i);
                if (a2r == 0.0 && a2i == 0.0) continue;
                double pr = a1r * a2r - a1i * a2i;
                double pi = a1r * a2i + a1i * a2r;
                for (int kk = 0; kk < O2; ++kk) {
                    double C = su2cg(i, f, o, ii - i, jj - f, kk - o);
                    if (C == 0.0) continue;
                    double a3r, a3i; qval(o, cc, kk, a3r, a3i);
                    a3i = -a3i;
                    if (a3r == 0.0 && a3i == 0.0) continue;
                    double qr = pr * a3r - pi * a3i;
                    double qi = pr * a3i + pi * a3r;
                    re += qr * C;
                    im += qi * C;
                }
            }
        }
    }
    __shared__ double smre[128], smim[128];
    smre[t] = (t < sz) ? fabs(re) : 0.0;
    smim[t] = (t < sz) ? fabs(im) : 0.0;
    __syncthreads();
    __shared__ int useRe;
    if (t == 0) {
        double mr = 0.0, mi = 0.0;
        for (int k = 0; k < 128; ++k) {
            mr = fmax(mr, smre[k]);
            mi = fmax(mi, smim[k]);
        }
        useRe = (mr >= mi) ? 1 : 0;
    }
    __syncthreads();
    if (t < sz) out[dCGOFF[c] + t] = (float)(useRe ? re : im);
}

// ---------------------------------------------------------------------------
// Node input linears — row-vectorized (f32x4 loads/stores, static indices)
// ---------------------------------------------------------------------------
__global__ void ins_kernel(const float* __restrict__ x0, const float* __restrict__ x1,
                           const float* __restrict__ x2,
                           const float* __restrict__ Wl0, const float* __restrict__ Wl1,
                           const float* __restrict__ Wl2,
                           float* __restrict__ ins0, float* __restrict__ ins1,
                           float* __restrict__ ins2, int Nn) {
    int n = blockIdx.x * blockDim.x + threadIdx.x;
    if (n >= Nn) return;
    const float inv = 0.28867513459481287f;  // 1/sqrt(12)
    // l = 0
    {
        float xl[12];
#pragma unroll
        for (int k = 0; k < 3; ++k) {
            f32x4 v = *(const f32x4*)(x0 + (size_t)n * 12 + 4 * k);
#pragma unroll
            for (int j = 0; j < 4; ++j) xl[4 * k + j] = v[j];
        }
        float o[12];
#pragma unroll
        for (int v = 0; v < 12; ++v) {
            float s = 0.f;
#pragma unroll
            for (int u = 0; u < 12; ++u) s = fmaf(Wl0[v * 12 + u], xl[u], s);
            o[v] = s * inv;
        }
#pragma unroll
        for (int k = 0; k < 3; ++k) {
            f32x4 w = {o[4 * k], o[4 * k + 1], o[4 * k + 2], o[4 * k + 3]};
            *(f32x4*)(ins0 + (size_t)n * 12 + 4 * k) = w;
        }
    }
    // l = 1
    {
        float row[36];
#pragma unroll
        for (int k = 0; k < 9; ++k) {
            f32x4 v = *(const f32x4*)(x1 + (size_t)n * 36 + 4 * k);
#pragma unroll
            for (int j = 0; j < 4; ++j) row[4 * k + j] = v[j];
        }
        float o[36];
#pragma unroll
        for (int m = 0; m < 3; ++m)
#pragma unroll
            for (int v = 0; v < 12; ++v) {
                float s = 0.f;
#pragma unroll
                for (int u = 0; u < 12; ++u)
                    s = fmaf(Wl1[v * 12 + u], row[u * 3 + m], s);
                o[v * 3 + m] = s * inv;
            }
#pragma unroll
        for (int k = 0; k < 9; ++k) {
            f32x4 w = {o[4 * k], o[4 * k + 1], o[4 * k + 2], o[4 * k + 3]};
            *(f32x4*)(ins1 + (size_t)n * 36 + 4 * k) = w;
        }
    }
    // l = 2
    {
        float row[60];
#pragma unroll
        for (int k = 0; k < 15; ++k) {
            f32x4 v = *(const f32x4*)(x2 + (size_t)n * 60 + 4 * k);
#pragma unroll
            for (int j = 0; j < 4; ++j) row[4 * k + j] = v[j];
        }
        float o[60];
#pragma unroll
        for (int m = 0; m < 5; ++m)
#pragma unroll
            for (int v = 0; v < 12; ++v) {
                float s = 0.f;
#pragma unroll
                for (int u = 0; u < 12; ++u)
                    s = fmaf(Wl2[v * 12 + u], row[u * 5 + m], s);
                o[v * 5 + m] = s * inv;
            }
#pragma unroll
        for (int k = 0; k < 15; ++k) {
            f32x4 w = {o[4 * k], o[4 * k + 1], o[4 * k + 2], o[4 * k + 3]};
            *(f32x4*)(ins2 + (size_t)n * 60 + 4 * k) = w;
        }
    }
}

// ---------------------------------------------------------------------------
// CSR build: histogram -> exclusive scan -> cursor fill
// ---------------------------------------------------------------------------
__global__ void hist_kernel(const int* __restrict__ eidx, int* __restrict__ counts,
                            int Ee) {
    int e = blockIdx.x * blockDim.x + threadIdx.x;
    if (e >= Ee) return;
    atomicAdd(&counts[eidx[Ee + e]], 1);
}

__global__ void scan_kernel(const int* __restrict__ counts, int* __restrict__ offs,
                            int* __restrict__ cursor, int Nn, int Ee) {
    __shared__ int part[256];
    int t = threadIdx.x;
    const int CH = (Nn + 255) / 256;
    int base = t * CH;
    int s = 0;
    for (int k = 0; k < CH; ++k) {
        int i = base + k;
        if (i < Nn) s += counts[i];
    }
    part[t] = s;
    __syncthreads();
    for (int off = 1; off < 256; off <<= 1) {
        int v = (t >= off) ? part[t - off] : 0;
        __syncthreads();
        part[t] += v;
        __syncthreads();
    }
    int pre = (t == 0) ? 0 : part[t - 1];
    for (int k = 0; k < CH; ++k) {
        int i = base + k;
        if (i < Nn) {
            offs[i] = pre;
            cursor[i] = pre;
            pre += counts[i];
        }
    }
    if (t == 255) offs[Nn] = Ee;
}

__global__ void fill_kernel(const int* __restrict__ eidx, int* __restrict__ cursor,
                            int* __restrict__ elist, int Ee) {
    int e = blockIdx.x * blockDim.x + threadIdx.x;
    if (e >= Ee) return;
    int r = atomicAdd(&cursor[eidx[Ee + e]], 1);
    elist[r] = e;
}

// ---------------------------------------------------------------------------
// rW2 -> pre-swizzled bf16 hi/lo fragments (A operand of mfma(A=rW2tile,B=h)).
// Lane l of tile t holds rW2[k=8*(l>>4)+j][n=16*t+(l&15)], j=0..7.
// ---------------------------------------------------------------------------
__global__ void bfrag_setup(const float* __restrict__ rW2,
                            unsigned short* __restrict__ bfH,
                            unsigned short* __restrict__ bfL) {
    int blk = blockIdx.x;            // c*9 + t
    int c = blk / 9, t = blk % 9;
    int lane = threadIdx.x;
    int k0 = 8 * (lane >> 4);
    int n = 16 * t + (lane & 15);    // n = v*12+u in [0,144)
    size_t base = ((size_t)blk * 64 + lane) * 8;
#pragma unroll
    for (int j = 0; j < 8; ++j) {
        float val = rW2[(size_t)(c * 32 + k0 + j) * 144 + n];
        unsigned short hi = bfhi(val);
        bfH[base + j] = hi;
        bfL[base + j] = bfhi(val - bff(hi));
    }
}

// ---------------------------------------------------------------------------
// esort: permute edge data into CSR (elist) order, padded q-slice layout.
// ---------------------------------------------------------------------------
__global__ void esort_kernel(const int* __restrict__ eidx, const int* __restrict__ elist,
                             const float* __restrict__ edge_attr,
                             const float* __restrict__ ins0, const float* __restrict__ ins1,
                             const float* __restrict__ ins2,
                             float* __restrict__ eattr4,
                             float* __restrict__ xi0s, float* __restrict__ xi1s,
                             float* __restrict__ xi2s, int Ee) {
    int r = blockIdx.x * blockDim.x + threadIdx.x;
    if (r >= Ee) return;
    int e = elist[r];
    int src = eidx[e];
    int dst = eidx[Ee + e];
    f32x4 ea;
    ea[0] = edge_attr[3 * e + 0];
    ea[1] = edge_attr[3 * e + 1];
    ea[2] = edge_attr[3 * e + 2];
    ea[3] = __int_as_float(dst);
    *(f32x4*)(eattr4 + (size_t)r * 4) = ea;

    {
        const f32x4* s = (const f32x4*)(ins0 + (size_t)src * 12);
        f32x4 a0 = s[0], a1 = s[1], a2 = s[2];
        float row[12];
#pragma unroll
        for (int k = 0; k < 4; ++k) { row[k] = a0[k]; row[4 + k] = a1[k]; row[8 + k] = a2[k]; }
#pragma unroll
        for (int q = 0; q < 4; ++q) {
            f32x4 w = {row[3 * q], row[3 * q + 1], row[3 * q + 2], 0.f};
            *(f32x4*)(xi0s + (size_t)r * 16 + q * 4) = w;
        }
    }
    {
        const f32x4* s = (const f32x4*)(ins1 + (size_t)src * 36);
        float row[36];
#pragma unroll
        for (int v = 0; v < 9; ++v) {
            f32x4 a = s[v];
#pragma unroll
            for (int k = 0; k < 4; ++k) row[4 * v + k] = a[k];
        }
#pragma unroll
        for (int q = 0; q < 4; ++q) {
#pragma unroll
            for (int c4 = 0; c4 < 3; ++c4) {
                f32x4 w;
#pragma unroll
                for (int k = 0; k < 4; ++k) {
                    int j = 4 * c4 + k;
                    w[k] = (j < 9) ? row[9 * q + j] : 0.f;
                }
                *(f32x4*)(xi1s + (size_t)r * 48 + q * 12 + c4 * 4) = w;
            }
        }
    }
    {
        const f32x4* s = (const f32x4*)(ins2 + (size_t)src * 60);
        float row[60];
#pragma unroll
        for (int v = 0; v < 15; ++v) {
            f32x4 a = s[v];
#pragma unroll
            for (int k = 0; k < 4; ++k) row[4 * v + k] = a[k];
        }
#pragma unroll
        for (int q = 0; q < 4; ++q) {
#pragma unroll
            for (int c4 = 0; c4 < 4; ++c4) {
                f32x4 w;
#pragma unroll
                for (int k = 0; k < 4; ++k) {
                    int j = 4 * c4 + k;
                    w[k] = (j < 15) ? row[15 * q + j] : 0.f;
                }
                *(f32x4*)(xi2s + (size_t)r * 64 + q * 16 + c4 * 4) = w;
            }
        }
    }
}

// ---------------------------------------------------------------------------
// Gather with MFMA Wr: block = 1 wave, (combo, DG-dst CSR range).
// rW1/rb1 + rW2 frags in registers; segmented-scan scatter; 2 fences/tile.
// ---------------------------------------------------------------------------
template <int I, int F, int O, int C, int RANK>
__device__ __forceinline__ void gather_mfma(
    const int* __restrict__ offs,
    const float* __restrict__ rW1, const float* __restrict__ rb1,
    const unsigned short* __restrict__ bfH, const unsigned short* __restrict__ bfL,
    const float* __restrict__ cg,
    const float* __restrict__ eattr4, const float* __restrict__ xis,
    float* __restrict__ accO, int accStride,
    float* __restrict__ s_zbuf, float* __restrict__ s_wr, float* __restrict__ s_acc,
    int d0, int dGc, int estart, int eend) {
    constexpr int I2 = 2 * I + 1, F2 = 2 * F + 1, O2 = 2 * O + 1;
    constexpr int SA = 12 * O2;       // acc floats per dst
    constexpr int ZP = 68;            // zbuf row stride
    constexpr int WP = 148;           // s_wr row stride (144 cols + pad)
    constexpr int PQ = (I2 == 1) ? 4 : (I2 == 3) ? 12 : 16;   // floats per q-slice
    constexpr int PE = 4 * PQ;                                 // floats per edge
    const float inv = 0.28867513459481287f;  // 1/sqrt(12)
    const int lane = threadIdx.x;
    const int e = lane & 15;          // edge slot in tile
    const int q = lane >> 4;          // quarter 0..3

    for (int t = lane; t < DG * SA; t += GT) s_acc[t] = 0.f;
    LDS_FENCE();

    if (estart < eend) {
        // hoist rW2 fragments into registers
        bf16x8 wfH[9], wfL[9];
#pragma unroll
        for (int t9 = 0; t9 < 9; ++t9) {
            size_t boff = ((size_t)(C * 9 + t9) * 64 + lane) * 8;
            wfH[t9] = *(const bf16x8*)(bfH + boff);
            wfL[t9] = *(const bf16x8*)(bfL + boff);
        }
        // hoist rW1 slice + rb1 into registers (loop-invariant)
        float rw1r[10][8];
        float rb1r[8];
#pragma unroll
        for (int b = 0; b < 10; ++b)
#pragma unroll
            for (int j = 0; j < 8; ++j)
                rw1r[b][j] = rW1[(C * 10 + b) * 32 + 8 * q + j];
#pragma unroll
        for (int j = 0; j < 8; ++j) rb1r[j] = rb1[C * 32 + 8 * q + j];

        auto load_xi = [&](int rc, float (&xi)[3][I2]) {
            const f32x4* xp = (const f32x4*)(xis + (size_t)rc * PE + q * PQ);
            if constexpr (I2 == 1) {
                f32x4 v0 = xp[0];
                xi[0][0] = v0[0]; xi[1][0] = v0[1]; xi[2][0] = v0[2];
            } else if constexpr (I2 == 3) {
                f32x4 v0 = xp[0], v1 = xp[1], v2 = xp[2];
#pragma unroll
                for (int uu = 0; uu < 3; ++uu)
#pragma unroll
                    for (int a = 0; a < 3; ++a) {
                        int j = uu * 3 + a;
                        xi[uu][a] = (j < 4) ? v0[j] : (j < 8) ? v1[j - 4] : v2[j - 8];
                    }
            } else {
                f32x4 v0 = xp[0], v1 = xp[1], v2 = xp[2], v3 = xp[3];
#pragma unroll
                for (int uu = 0; uu < 3; ++uu)
#pragma unroll
                    for (int a = 0; a < 5; ++a) {
                        int j = uu * 5 + a;
                        xi[uu][a] = (j < 4) ? v0[j] : (j < 8) ? v1[j - 4]
                                  : (j < 12) ? v2[j - 8] : v3[j - 12];
                    }
            }
        };

        // ---- prime tile 0 ----
        int r0 = estart + e;
        bool valid = (r0 < eend);
        int rc = valid ? r0 : (eend - 1);
        f32x4 ea = *(const f32x4*)(eattr4 + (size_t)rc * 4);
        float xi[3][I2];
        load_xi(rc, xi);

        for (int tile = estart; tile < eend; tile += 16) {
            bool hasN = (tile + 16) < eend;
            int rN = tile + 16 + e;
            bool validN = (rN < eend);
            int rNc = validN ? rN : (eend - 1);

            int dst = __float_as_int(ea[3]);
            int local = dst - d0;
            float ex = ea[0], ey = ea[1], ez = ea[2];

            // segmented-scan masks for same-dst runs (elist is dst-sorted)
            int dstv = valid ? dst : (-1 - e);
            int du1 = __shfl_up(dstv, 1);
            int du2 = __shfl_up(dstv, 2);
            int du4 = __shfl_up(dstv, 4);
            int du8 = __shfl_up(dstv, 8);
            bool m1 = (e >= 1) && (du1 == dstv);
            bool m2 = (e >= 2) && (du2 == dstv);
            bool m4 = (e >= 4) && (du4 == dstv);
            bool m8 = (e >= 8) && (du8 == dstv);
            int dn = __shfl_down(dstv, 1);
            bool isEnd = (e == 15) || (dn != dstv);

            float d = sqrtf(ex * ex + ey * ey + ez * ez);
            float ri = 1.0f / fmaxf(d, 1e-9f);
            float x = ex * ri, y = ey * ri, zz = ez * ri;

            float rbf[10];
#pragma unroll
            for (int b = 0; b < 10; ++b) {
                float tt = d - 0.3888888888888889f * (float)b;
                rbf[b] = __expf(-4.0f * tt * tt);
            }

            // h slice (B-operand layout): pure register FMA
            bf16x8 hH, hL;
            {
#pragma unroll
                for (int j = 0; j < 8; ++j) {
                    float a = rb1r[j];
#pragma unroll
                    for (int b = 0; b < 10; ++b)
                        a = fmaf(rbf[b], rw1r[b][j], a);
                    a = fmaxf(a, 0.0f);
                    if (!valid) a = 0.0f;
                    unsigned short hi = bfhi(a);
                    hH[j] = (short)hi;
                    hL[j] = (short)bfhi(a - bff(hi));
                }
            }

            // prefetch next tile's eattr (linear address, in place)
            if (hasN) ea = *(const f32x4*)(eattr4 + (size_t)rNc * 4);

            // spherical harmonics (order F only)
            float Yf[F2];
            if constexpr (F == 0) {
                Yf[0] = 1.0f;
            } else if constexpr (F == 1) {
                const float s3 = 1.7320508075688772f;
                Yf[0] = s3 * y; Yf[1] = s3 * zz; Yf[2] = s3 * x;
            } else {
                const float s15 = 3.872983346207417f;
                const float s5 = 2.2360679774997896f;
                Yf[0] = s15 * x * y;
                Yf[1] = s15 * y * zz;
                Yf[2] = 0.5f * s5 * (3.0f * zz * zz - 1.0f);
                Yf[3] = s15 * x * zz;
                Yf[4] = 0.5f * s15 * (x * x - y * y);
            }

            // kY[a][oo] = sum_j CG[a,j,oo] * Yf[j]
            float kY[I2][O2];
#pragma unroll
            for (int a = 0; a < I2; ++a)
#pragma unroll
                for (int oo = 0; oo < O2; ++oo) {
                    float s = 0.f;
#pragma unroll
                    for (int j = 0; j < F2; ++j)
                        s = fmaf(cg[kCGOFF[C] + (a * F2 + j) * O2 + oo], Yf[j], s);
                    kY[a][oo] = s;
                }

            // z rows u = 3q..3q+2 from xi -> zbuf (last use of xi)
#pragma unroll
            for (int uu = 0; uu < 3; ++uu) {
                int u = 3 * q + uu;
#pragma unroll
                for (int oo = 0; oo < O2; ++oo) {
                    float s = 0.f;
#pragma unroll
                    for (int a = 0; a < I2; ++a) s = fmaf(xi[uu][a], kY[a][oo], s);
                    s_zbuf[e * ZP + u * O2 + oo] = s;
                }
            }

            // prefetch next tile's xi (linear address, in place)
            if (hasN) load_xi(rNc, xi);

            // MFMA phase: all 9 col-tiles, pure register inputs
#pragma unroll
            for (int t9 = 0; t9 < 9; ++t9) {
                f32x4 a4 = {0.f, 0.f, 0.f, 0.f};
                a4 = __builtin_amdgcn_mfma_f32_16x16x32_bf16(wfH[t9], hH, a4, 0, 0, 0);
                a4 = __builtin_amdgcn_mfma_f32_16x16x32_bf16(wfL[t9], hH, a4, 0, 0, 0);
                a4 = __builtin_amdgcn_mfma_f32_16x16x32_bf16(wfH[t9], hL, a4, 0, 0, 0);
                // lane (e,q) holds Wr[e][16*t9 + 4q + rg] -> b128 store
                *(f32x4*)&s_wr[e * WP + 16 * t9 + 4 * q] = a4;
            }
            LDS_FENCE();   // zbuf + s_wr visible

            // consumer: lane (e,q) -> edge e, v = 4g+q for g = 0..2
#pragma unroll
            for (int g = 0; g < 3; ++g) {
                f32x4 w0 = *(const f32x4*)&s_wr[e * WP + 48 * g + 12 * q + 0];
                f32x4 w1 = *(const f32x4*)&s_wr[e * WP + 48 * g + 12 * q + 4];
                f32x4 w2 = *(const f32x4*)&s_wr[e * WP + 48 * g + 12 * q + 8];

                float msg[O2];
#pragma unroll
                for (int oo = 0; oo < O2; ++oo) msg[oo] = 0.f;
#pragma unroll
                for (int u4 = 0; u4 < 4; ++u4) {
#pragma unroll
                    for (int oo = 0; oo < O2; ++oo) {
                        msg[oo] = fmaf(w0[u4], s_zbuf[e * ZP + u4 * O2 + oo], msg[oo]);
                        msg[oo] = fmaf(w1[u4], s_zbuf[e * ZP + (4 + u4) * O2 + oo], msg[oo]);
                        msg[oo] = fmaf(w2[u4], s_zbuf[e * ZP + (8 + u4) * O2 + oo], msg[oo]);
                    }
                }
#pragma unroll
                for (int oo = 0; oo < O2; ++oo) {
                    float v = msg[oo] * inv;
                    float t1 = __shfl_up(v, 1); if (m1) v += t1;
                    float t2 = __shfl_up(v, 2); if (m2) v += t2;
                    float t4 = __shfl_up(v, 4); if (m4) v += t4;
                    float t8 = __shfl_up(v, 8); if (m8) v += t8;
                    if (isEnd && valid)
                        unsafeAtomicAdd(&s_acc[local * SA + (4 * g + q) * O2 + oo], v);
                }
            }
            LDS_FENCE();   // WAR: next tile rewrites zbuf / s_wr

            valid = validN;
        }
    }

    LDS_FENCE();
    for (int t = lane; t < dGc * SA; t += GT) {
        int local = t / SA;
        int comp = t - local * SA;
        accO[(size_t)(d0 + local) * accStride + RANK * SA + comp] =
            s_acc[local * SA + comp];
    }
}

__global__ __launch_bounds__(GT) void gather_kernel(
    const int* __restrict__ offs,
    const float* __restrict__ rW1, const float* __restrict__ rb1,
    const unsigned short* __restrict__ bfH, const unsigned short* __restrict__ bfL,
    const float* __restrict__ cg,
    const float* __restrict__ eattr4,
    const float* __restrict__ xi0s, const float* __restrict__ xi1s,
    const float* __restrict__ xi2s,
    float* __restrict__ acc0, float* __restrict__ acc1, float* __restrict__ acc2,
    int Nn) {
    __shared__ __align__(16) float s_zbuf[16 * 68];
    __shared__ __align__(16) float s_wr[16 * 148];
    __shared__ __align__(16) float s_acc[DG * 60];
    int nb = (Nn + DG - 1) / DG;
    int cidx = blockIdx.x / nb;
    int dblk = blockIdx.x - cidx * nb;
    int combo = dCORDER[cidx];
    int d0 = dblk * DG;
    int dGc = Nn - d0;
    if (dGc > DG) dGc = DG;
    int estart = offs[d0];
    int eend = offs[d0 + dGc];

    switch (combo) {
    case 0:  gather_mfma<0,0,0, 0,0>(offs, rW1, rb1, bfH, bfL, cg, eattr4, xi0s, acc0,  36, s_zbuf, s_wr, s_acc, d0, dGc, estart, eend); break;
    case 1:  gather_mfma<0,1,1, 1,0>(offs, rW1, rb1, bfH, bfL, cg, eattr4, xi0s, acc1, 216, s_zbuf, s_wr, s_acc, d0, dGc, estart, eend); break;
    case 2:  gather_mfma<0,2,2, 2,0>(offs, rW1, rb1, bfH, bfL, cg, eattr4, xi0s, acc2, 360, s_zbuf, s_wr, s_acc, d0, dGc, estart, eend); break;
    case 3:  gather_mfma<1,0,1, 3,1>(offs, rW1, rb1, bfH, bfL, cg, eattr4, xi1s, acc1, 216, s_zbuf, s_wr, s_acc, d0, dGc, estart, eend); break;
    case 4:  gather_mfma<1,1,0, 4,1>(offs, rW1, rb1, bfH, bfL, cg, eattr4, xi1s, acc0,  36, s_zbuf, s_wr, s_acc, d0, dGc, estart, eend); break;
    case 5:  gather_mfma<1,1,1, 5,2>(offs, rW1, rb1, bfH, bfL, cg, eattr4, xi1s, acc1, 216, s_zbuf, s_wr, s_acc, d0, dGc, estart, eend); break;
    case 6:  gather_mfma<1,1,2, 6,1>(offs, rW1, rb1, bfH, bfL, cg, eattr4, xi1s, acc2, 360, s_zbuf, s_wr, s_acc, d0, dGc, estart, eend); break;
    case 7:  gather_mfma<1,2,1, 7,3>(offs, rW1, rb1, bfH, bfL, cg, eattr4, xi1s, acc1, 216, s_zbuf, s_wr, s_acc, d0, dGc, estart, eend); break;
    case 8:  gather_mfma<1,2,2, 8,2>(offs, rW1, rb1, bfH, bfL, cg, eattr4, xi1s, acc2, 360, s_zbuf, s_wr, s_acc, d0, dGc, estart, eend); break;
    case 9:  gather_mfma<2,0,2, 9,3>(offs, rW1, rb1, bfH, bfL, cg, eattr4, xi2s, acc2, 360, s_zbuf, s_wr, s_acc, d0, dGc, estart, eend); break;
    case 10: gather_mfma<2,1,1,10,4>(offs, rW1, rb1, bfH, bfL, cg, eattr4, xi2s, acc1, 216, s_zbuf, s_wr, s_acc, d0, dGc, estart, eend); break;
    case 11: gather_mfma<2,1,2,11,4>(offs, rW1, rb1, bfH, bfL, cg, eattr4, xi2s, acc2, 360, s_zbuf, s_wr, s_acc, d0, dGc, estart, eend); break;
    case 12: gather_mfma<2,2,0,12,2>(offs, rW1, rb1, bfH, bfL, cg, eattr4, xi2s, acc0,  36, s_zbuf, s_wr, s_acc, d0, dGc, estart, eend); break;
    case 13: gather_mfma<2,2,1,13,5>(offs, rW1, rb1, bfH, bfL, cg, eattr4, xi2s, acc1, 216, s_zbuf, s_wr, s_acc, d0, dGc, estart, eend); break;
    case 14: gather_mfma<2,2,2,14,5>(offs, rW1, rb1, bfH, bfL, cg, eattr4, xi2s, acc2, 360, s_zbuf, s_wr, s_acc, d0, dGc, estart, eend); break;
    }
}

// ---------------------------------------------------------------------------
// Output linears + activations: wave-per-node, LDS-staged acc row,
// lane-per-component, shuffle norms.
// ---------------------------------------------------------------------------
__global__ __launch_bounds__(256) void out_kernel(
    const float* __restrict__ acc0, const float* __restrict__ acc1,
    const float* __restrict__ acc2,
    const float* __restrict__ Wo0, const float* __restrict__ Wo1,
    const float* __restrict__ Wo2,
    float* __restrict__ out, int Nn) {
    __shared__ __align__(16) float s_a[4 * 612];
    const int wid = threadIdx.x >> 6;
    const int lane = threadIdx.x & 63;
    const int n = blockIdx.x * 4 + wid;
    if (n >= Nn) return;               // wave-uniform
    float* sa = s_a + wid * 612;

    // stage acc rows (612 floats) coalesced
    for (int t = lane; t < 153; t += 64) {
        f32x4 v;
        if (t < 9)       v = *(const f32x4*)(acc0 + (size_t)n * 36 + 4 * t);
        else if (t < 63) v = *(const f32x4*)(acc1 + (size_t)n * 216 + 4 * (t - 9));
        else             v = *(const f32x4*)(acc2 + (size_t)n * 360 + 4 * (t - 63));
        *(f32x4*)(sa + 4 * t) = v;
    }
    LDS_FENCE();   // wave-private slice

    // phase 0: o0, lanes 0-11 (v = lane)
    {
        int v = (lane < 12) ? lane : 0;
        float s = 0.f;
#pragma unroll
        for (int u = 0; u < 36; ++u) s = fmaf(Wo0[v * 36 + u], sa[u], s);
        s *= (1.0f / 6.0f);
        float r = s / (1.0f + __expf(-s));
        if (lane < 12) out[(size_t)n * 12 + v] = r;
    }
    // phase 1: o1, lanes 0-35 (v = l/3, m = l%3)
    {
        int l = (lane < 36) ? lane : 0;
        int v = l / 3, m = l - 3 * (l / 3);
        float y = 0.f;
#pragma unroll
        for (int u = 0; u < 72; ++u)
            y = fmaf(Wo1[v * 72 + u], sa[36 + u * 3 + m], y);
        y *= 0.11785113019775793f;  // 1/sqrt(72)
        int base = l - m;
        float y0 = __shfl(y, base + 0);
        float y1 = __shfl(y, base + 1);
        float y2 = __shfl(y, base + 2);
        float nr = sqrtf(y0 * y0 + y1 * y1 + y2 * y2);
        float g = (nr / (1.0f + __expf(-nr))) / fmaxf(nr, 1e-9f);
        if (lane < 36) out[(size_t)Nn * 12 + (size_t)n * 36 + v * 3 + m] = y * g;
    }
    // phase 2: o2, lanes 0-59 (v = l/5, m = l%5)
    {
        int l = (lane < 60) ? lane : 0;
        int v = l / 5, m = l - 5 * (l / 5);
        float y = 0.f;
#pragma unroll
        for (int u = 0; u < 72; ++u)
            y = fmaf(Wo2[v * 72 + u], sa[252 + u * 5 + m], y);
        y *= 0.11785113019775793f;  // 1/sqrt(72)
        int base = l - m;
        float nr2 = 0.f;
#pragma unroll
        for (int k = 0; k < 5; ++k) {
            float t = __shfl(y, base + k);
            nr2 = fmaf(t, t, nr2);
        }
        float nr = sqrtf(nr2);
        float g = (nr / (1.0f + __expf(-nr))) / fmaxf(nr, 1e-9f);
        if (lane < 60) out[(size_t)Nn * 48 + (size_t)n * 60 + v * 5 + m] = y * g;
    }
}

// ---------------------------------------------------------------------------
extern "C" void kernel_launch(void* const* d_in, const int* in_sizes, int n_in,
                              void* d_out, int out_size, void* d_ws, size_t ws_size,
                              hipStream_t stream) {
    const float* x0 = (const float*)d_in[0];
    const float* x1 = (const float*)d_in[1];
    const float* x2 = (const float*)d_in[2];
    const float* edge_attr = (const float*)d_in[3];
    const float* Wl0 = (const float*)d_in[4];
    const float* Wl1 = (const float*)d_in[5];
    const float* Wl2 = (const float*)d_in[6];
    const float* rW1 = (const float*)d_in[7];
    const float* rb1 = (const float*)d_in[8];
    const float* rW2 = (const float*)d_in[9];
    const float* Wo0 = (const float*)d_in[10];
    const float* Wo1 = (const float*)d_in[11];
    const float* Wo2 = (const float*)d_in[12];
    const int* eidx = (const int*)d_in[13];
    float* out = (float*)d_out;

    const int Nn = in_sizes[0] / 12;   // 10000
    const int Ee = in_sizes[3] / 3;    // 128000

    float* ws = (float*)d_ws;
    float* cg = ws;                                   // 640
    float* ins0 = ws + 640;                           // N*12
    float* ins1 = ins0 + (size_t)Nn * 12;             // N*36
    float* ins2 = ins1 + (size_t)Nn * 36;             // N*60
    float* acc0 = ins2 + (size_t)Nn * 60;             // N*36
    float* acc1 = acc0 + (size_t)Nn * 36;             // N*216
    float* acc2 = acc1 + (size_t)Nn * 216;            // N*360
    int* counts = (int*)(acc2 + (size_t)Nn * 360);    // N
    int* offs   = counts + Nn;                        // N+1
    int* cursor = offs + Nn + 1;                      // N
    int* elist  = cursor + Nn;                        // E
    size_t intEnd = (size_t)((char*)(elist + Ee) - (char*)d_ws);
    size_t bOff = (intEnd + 255) & ~(size_t)255;      // 16B-align bf16 frags
    unsigned short* bfH = (unsigned short*)((char*)d_ws + bOff);
    unsigned short* bfL = bfH + (size_t)NCOMB * 9 * 64 * 8;
    float* eattr4 = (float*)(bfL + (size_t)NCOMB * 9 * 64 * 8);
    float* xi0s = eattr4 + (size_t)Ee * 4;
    float* xi1s = xi0s + (size_t)Ee * 16;
    float* xi2s = xi1s + (size_t)Ee * 48;

    hipMemsetAsync(counts, 0, (size_t)Nn * sizeof(int), stream);

    cg_setup<<<NCOMB, 128, 0, stream>>>(cg);
    ins_kernel<<<(Nn + 255) / 256, 256, 0, stream>>>(x0, x1, x2, Wl0, Wl1, Wl2,
                                                     ins0, ins1, ins2, Nn);
    hist_kernel<<<(Ee + 255) / 256, 256, 0, stream>>>(eidx, counts, Ee);
    scan_kernel<<<1, 256, 0, stream>>>(counts, offs, cursor, Nn, Ee);
    fill_kernel<<<(Ee + 255) / 256, 256, 0, stream>>>(eidx, cursor, elist, Ee);
    bfrag_setup<<<NCOMB * 9, 64, 0, stream>>>(rW2, bfH, bfL);
    esort_kernel<<<(Ee + 255) / 256, 256, 0, stream>>>(eidx, elist, edge_attr,
                                                       ins0, ins1, ins2,
                                                       eattr4, xi0s, xi1s, xi2s, Ee);

    int nb = (Nn + DG - 1) / DG;
    gather_kernel<<<nb * NCOMB, GT, 0, stream>>>(offs, rW1, rb1, bfH, bfL, cg,
                                                 eattr4, xi0s, xi1s, xi2s,
                                                 acc0, acc1, acc2, Nn);

    out_kernel<<<(Nn + 3) / 4, 256, 0, stream>>>(acc0, acc1, acc2,
                                                 Wo0, Wo1, Wo2, out, Nn);
}

// Round 19
// 665.086 us; speedup vs baseline: 1.0062x; 1.0062x over previous
//
#include <hip/hip_runtime.h>
#include <math.h>

// ---------------------------------------------------------------------------
// E3NN conv: N=10000 nodes, E=128000 edges, MUL=12, B=10 rbf, H=32 hidden.
// 15 combos (i,f,o). Outputs: o0 (N,12), o1 (N,36), o2 (N,60) concat flat.
//
// Round 19: r18 (verified 669us baseline) + two low-risk levers:
//  - DG 16->32: halves grid (9375->4695 blocks); amortizes the per-block
//    preamble (frag/rW1 register hoists, s_acc zero) over ~26 tiles not ~13
//  - s_setprio(1) around the MFMA phase: independent 1-wave blocks at
//    different phases share a SIMD -> scheduler hint favors the MFMA wave
//    (the attn-like regime where this measured +4-7%)
// Everything else identical to the verified r15/r18 kernel.
// ---------------------------------------------------------------------------

#define NCOMB 15
#define DG 32          // dsts per block
#define GT 64          // gather block threads (1 wave)

// LDS visibility fence for single-wave LDS slices: no s_barrier, no vmcnt drain.
#define LDS_FENCE() do { \
    asm volatile("s_waitcnt lgkmcnt(0)" ::: "memory"); \
    __builtin_amdgcn_sched_barrier(0); \
} while (0)

typedef float f32x4 __attribute__((ext_vector_type(4)));
typedef short bf16x8 __attribute__((ext_vector_type(8)));

constexpr int kCGOFF[NCOMB] = {0,1,10,35,44,53,80,125,170,245,270,315,390,415,490};

__device__ const int dCI[NCOMB]    = {0,0,0,1,1,1,1,1,1,2,2,2,2,2,2};
__device__ const int dCF[NCOMB]    = {0,1,2,0,1,1,1,2,2,0,1,1,2,2,2};
__device__ const int dCO[NCOMB]    = {0,1,2,1,0,1,2,1,2,2,1,2,0,1,2};
__device__ const int dCGOFF[NCOMB] = {0,1,10,35,44,53,80,125,170,245,270,315,390,415,490};
// heavy combos (O2=5, big I2*F2) first -> short scheduling tail
__device__ const int dCORDER[NCOMB] = {14,8,11,2,9,6,13,7,10,5,12,3,1,4,0};

// bf16 round-to-nearest-even helpers
__device__ __forceinline__ unsigned short bfhi(float f) {
    unsigned u = __float_as_uint(f);
    return (unsigned short)((u + 0x7FFFu + ((u >> 16) & 1u)) >> 16);
}
__device__ __forceinline__ float bff(unsigned short h) {
    return __uint_as_float(((unsigned)h) << 16);
}

// ---------------------------------------------------------------------------
// CG setup (bit-matches numpy: contract-off, numpy's r2, lexicographic order)
// ---------------------------------------------------------------------------
__device__ inline double dfact(int n) {
    double r = 1.0;
    for (int k = 2; k <= n; ++k) r *= (double)k;
    return r;
}

__device__ double su2cg(int j1, int j2, int j3, int m1, int m2, int m3) {
#pragma clang fp contract(off)
    if (m1 + m2 != m3) return 0.0;
    double pref = sqrt((2.0 * j3 + 1.0) * dfact(j3 + j1 - j2) * dfact(j3 - j1 + j2) *
                       dfact(j1 + j2 - j3) / dfact(j1 + j2 + j3 + 1));
    pref *= sqrt(dfact(j3 + m3) * dfact(j3 - m3) * dfact(j1 - m1) * dfact(j1 + m1) *
                 dfact(j2 - m2) * dfact(j2 + m2));
    int k0 = 0;
    if (j2 - j3 - m1 > k0) k0 = j2 - j3 - m1;
    if (j1 - j3 + m2 > k0) k0 = j1 - j3 + m2;
    int k1 = j1 + j2 - j3;
    if (j1 - m1 < k1) k1 = j1 - m1;
    if (j2 + m2 < k1) k1 = j2 + m2;
    double s = 0.0;
    for (int k = k0; k <= k1; ++k) {
        double t = 1.0 / (dfact(k) * dfact(j1 + j2 - j3 - k) * dfact(j1 - m1 - k) *
                          dfact(j2 + m2 - k) * dfact(j3 - j2 + m1 + k) * dfact(j3 - j1 - m2 + k));
        s += (k & 1) ? -t : t;
    }
    return pref * s;
}

__device__ inline void qval(int l, int r, int c, double& re, double& im) {
#pragma clang fp contract(off)
    re = 0.0; im = 0.0;
    const double r2 = __longlong_as_double(0x3FE6A09E667F3BCCLL);  // numpy 1/sqrt(2)
    int m = r - l;
    if (m == 0) { if (c == l) re = 1.0; return; }
    if (m < 0) {
        if (c == r) im = -r2;
        else if (c == 2 * l - r) re = r2;
    } else {
        double sg = (m & 1) ? -1.0 : 1.0;
        if (c == r) re = sg * r2;
        else if (c == 2 * l - r) im = sg * r2;
    }
}

__global__ void cg_setup(float* __restrict__ out) {
#pragma clang fp contract(off)
    int c = blockIdx.x;
    if (c >= NCOMB) return;
    const int i = dCI[c], f = dCF[c], o = dCO[c];
    const int I2 = 2 * i + 1, F2 = 2 * f + 1, O2 = 2 * o + 1;
    const int sz = I2 * F2 * O2;
    const int t = threadIdx.x;

    double re = 0.0, im = 0.0;
    if (t < sz) {
        int a = t / (F2 * O2);
        int rem = t % (F2 * O2);
        int b = rem / O2;
        int cc = rem % O2;
        for (int ii = 0; ii < I2; ++ii) {
            double a1r, a1i; qval(i, a, ii, a1r, a1i);
            if (a1r == 0.0 && a1i == 0.0) continue;
            for (int jj = 0; jj < F2; ++jj) {
                double a2r, a2i; qval(f, b, jj, a2r, a2i);
                if (a2r == 0.0 && a2i == 0.0) continue;
                double pr = a1r * a2r - a1i * a2i;
                double pi = a1r * a2i + a1i * a2r;
                for (int kk = 0; kk < O2; ++kk) {
                    double C = su2cg(i, f, o, ii - i, jj - f, kk - o);
                    if (C == 0.0) continue;
                    double a3r, a3i; qval(o, cc, kk, a3r, a3i);
                    a3i = -a3i;
                    if (a3r == 0.0 && a3i == 0.0) continue;
                    double qr = pr * a3r - pi * a3i;
                    double qi = pr * a3i + pi * a3r;
                    re += qr * C;
                    im += qi * C;
                }
            }
        }
    }
    __shared__ double smre[128], smim[128];
    smre[t] = (t < sz) ? fabs(re) : 0.0;
    smim[t] = (t < sz) ? fabs(im) : 0.0;
    __syncthreads();
    __shared__ int useRe;
    if (t == 0) {
        double mr = 0.0, mi = 0.0;
        for (int k = 0; k < 128; ++k) {
            mr = fmax(mr, smre[k]);
            mi = fmax(mi, smim[k]);
        }
        useRe = (mr >= mi) ? 1 : 0;
    }
    __syncthreads();
    if (t < sz) out[dCGOFF[c] + t] = (float)(useRe ? re : im);
}

// ---------------------------------------------------------------------------
// Node input linears — row-vectorized (f32x4 loads/stores, static indices)
// ---------------------------------------------------------------------------
__global__ void ins_kernel(const float* __restrict__ x0, const float* __restrict__ x1,
                           const float* __restrict__ x2,
                           const float* __restrict__ Wl0, const float* __restrict__ Wl1,
                           const float* __restrict__ Wl2,
                           float* __restrict__ ins0, float* __restrict__ ins1,
                           float* __restrict__ ins2, int Nn) {
    int n = blockIdx.x * blockDim.x + threadIdx.x;
    if (n >= Nn) return;
    const float inv = 0.28867513459481287f;  // 1/sqrt(12)
    // l = 0
    {
        float xl[12];
#pragma unroll
        for (int k = 0; k < 3; ++k) {
            f32x4 v = *(const f32x4*)(x0 + (size_t)n * 12 + 4 * k);
#pragma unroll
            for (int j = 0; j < 4; ++j) xl[4 * k + j] = v[j];
        }
        float o[12];
#pragma unroll
        for (int v = 0; v < 12; ++v) {
            float s = 0.f;
#pragma unroll
            for (int u = 0; u < 12; ++u) s = fmaf(Wl0[v * 12 + u], xl[u], s);
            o[v] = s * inv;
        }
#pragma unroll
        for (int k = 0; k < 3; ++k) {
            f32x4 w = {o[4 * k], o[4 * k + 1], o[4 * k + 2], o[4 * k + 3]};
            *(f32x4*)(ins0 + (size_t)n * 12 + 4 * k) = w;
        }
    }
    // l = 1
    {
        float row[36];
#pragma unroll
        for (int k = 0; k < 9; ++k) {
            f32x4 v = *(const f32x4*)(x1 + (size_t)n * 36 + 4 * k);
#pragma unroll
            for (int j = 0; j < 4; ++j) row[4 * k + j] = v[j];
        }
        float o[36];
#pragma unroll
        for (int m = 0; m < 3; ++m)
#pragma unroll
            for (int v = 0; v < 12; ++v) {
                float s = 0.f;
#pragma unroll
                for (int u = 0; u < 12; ++u)
                    s = fmaf(Wl1[v * 12 + u], row[u * 3 + m], s);
                o[v * 3 + m] = s * inv;
            }
#pragma unroll
        for (int k = 0; k < 9; ++k) {
            f32x4 w = {o[4 * k], o[4 * k + 1], o[4 * k + 2], o[4 * k + 3]};
            *(f32x4*)(ins1 + (size_t)n * 36 + 4 * k) = w;
        }
    }
    // l = 2
    {
        float row[60];
#pragma unroll
        for (int k = 0; k < 15; ++k) {
            f32x4 v = *(const f32x4*)(x2 + (size_t)n * 60 + 4 * k);
#pragma unroll
            for (int j = 0; j < 4; ++j) row[4 * k + j] = v[j];
        }
        float o[60];
#pragma unroll
        for (int m = 0; m < 5; ++m)
#pragma unroll
            for (int v = 0; v < 12; ++v) {
                float s = 0.f;
#pragma unroll
                for (int u = 0; u < 12; ++u)
                    s = fmaf(Wl2[v * 12 + u], row[u * 5 + m], s);
                o[v * 5 + m] = s * inv;
            }
#pragma unroll
        for (int k = 0; k < 15; ++k) {
            f32x4 w = {o[4 * k], o[4 * k + 1], o[4 * k + 2], o[4 * k + 3]};
            *(f32x4*)(ins2 + (size_t)n * 60 + 4 * k) = w;
        }
    }
}

// ---------------------------------------------------------------------------
// CSR build: histogram -> exclusive scan -> cursor fill
// ---------------------------------------------------------------------------
__global__ void hist_kernel(const int* __restrict__ eidx, int* __restrict__ counts,
                            int Ee) {
    int e = blockIdx.x * blockDim.x + threadIdx.x;
    if (e >= Ee) return;
    atomicAdd(&counts[eidx[Ee + e]], 1);
}

__global__ void scan_kernel(const int* __restrict__ counts, int* __restrict__ offs,
                            int* __restrict__ cursor, int Nn, int Ee) {
    __shared__ int part[256];
    int t = threadIdx.x;
    const int CH = (Nn + 255) / 256;
    int base = t * CH;
    int s = 0;
    for (int k = 0; k < CH; ++k) {
        int i = base + k;
        if (i < Nn) s += counts[i];
    }
    part[t] = s;
    __syncthreads();
    for (int off = 1; off < 256; off <<= 1) {
        int v = (t >= off) ? part[t - off] : 0;
        __syncthreads();
        part[t] += v;
        __syncthreads();
    }
    int pre = (t == 0) ? 0 : part[t - 1];
    for (int k = 0; k < CH; ++k) {
        int i = base + k;
        if (i < Nn) {
            offs[i] = pre;
            cursor[i] = pre;
            pre += counts[i];
        }
    }
    if (t == 255) offs[Nn] = Ee;
}

__global__ void fill_kernel(const int* __restrict__ eidx, int* __restrict__ cursor,
                            int* __restrict__ elist, int Ee) {
    int e = blockIdx.x * blockDim.x + threadIdx.x;
    if (e >= Ee) return;
    int r = atomicAdd(&cursor[eidx[Ee + e]], 1);
    elist[r] = e;
}

// ---------------------------------------------------------------------------
// rW2 -> pre-swizzled bf16 hi/lo fragments (A operand of mfma(A=rW2tile,B=h)).
// Lane l of tile t holds rW2[k=8*(l>>4)+j][n=16*t+(l&15)], j=0..7.
// ---------------------------------------------------------------------------
__global__ void bfrag_setup(const float* __restrict__ rW2,
                            unsigned short* __restrict__ bfH,
                            unsigned short* __restrict__ bfL) {
    int blk = blockIdx.x;            // c*9 + t
    int c = blk / 9, t = blk % 9;
    int lane = threadIdx.x;
    int k0 = 8 * (lane >> 4);
    int n = 16 * t + (lane & 15);    // n = v*12+u in [0,144)
    size_t base = ((size_t)blk * 64 + lane) * 8;
#pragma unroll
    for (int j = 0; j < 8; ++j) {
        float val = rW2[(size_t)(c * 32 + k0 + j) * 144 + n];
        unsigned short hi = bfhi(val);
        bfH[base + j] = hi;
        bfL[base + j] = bfhi(val - bff(hi));
    }
}

// ---------------------------------------------------------------------------
// esort: permute edge data into CSR (elist) order, padded q-slice layout.
// ---------------------------------------------------------------------------
__global__ void esort_kernel(const int* __restrict__ eidx, const int* __restrict__ elist,
                             const float* __restrict__ edge_attr,
                             const float* __restrict__ ins0, const float* __restrict__ ins1,
                             const float* __restrict__ ins2,
                             float* __restrict__ eattr4,
                             float* __restrict__ xi0s, float* __restrict__ xi1s,
                             float* __restrict__ xi2s, int Ee) {
    int r = blockIdx.x * blockDim.x + threadIdx.x;
    if (r >= Ee) return;
    int e = elist[r];
    int src = eidx[e];
    int dst = eidx[Ee + e];
    f32x4 ea;
    ea[0] = edge_attr[3 * e + 0];
    ea[1] = edge_attr[3 * e + 1];
    ea[2] = edge_attr[3 * e + 2];
    ea[3] = __int_as_float(dst);
    *(f32x4*)(eattr4 + (size_t)r * 4) = ea;

    {
        const f32x4* s = (const f32x4*)(ins0 + (size_t)src * 12);
        f32x4 a0 = s[0], a1 = s[1], a2 = s[2];
        float row[12];
#pragma unroll
        for (int k = 0; k < 4; ++k) { row[k] = a0[k]; row[4 + k] = a1[k]; row[8 + k] = a2[k]; }
#pragma unroll
        for (int q = 0; q < 4; ++q) {
            f32x4 w = {row[3 * q], row[3 * q + 1], row[3 * q + 2], 0.f};
            *(f32x4*)(xi0s + (size_t)r * 16 + q * 4) = w;
        }
    }
    {
        const f32x4* s = (const f32x4*)(ins1 + (size_t)src * 36);
        float row[36];
#pragma unroll
        for (int v = 0; v < 9; ++v) {
            f32x4 a = s[v];
#pragma unroll
            for (int k = 0; k < 4; ++k) row[4 * v + k] = a[k];
        }
#pragma unroll
        for (int q = 0; q < 4; ++q) {
#pragma unroll
            for (int c4 = 0; c4 < 3; ++c4) {
                f32x4 w;
#pragma unroll
                for (int k = 0; k < 4; ++k) {
                    int j = 4 * c4 + k;
                    w[k] = (j < 9) ? row[9 * q + j] : 0.f;
                }
                *(f32x4*)(xi1s + (size_t)r * 48 + q * 12 + c4 * 4) = w;
            }
        }
    }
    {
        const f32x4* s = (const f32x4*)(ins2 + (size_t)src * 60);
        float row[60];
#pragma unroll
        for (int v = 0; v < 15; ++v) {
            f32x4 a = s[v];
#pragma unroll
            for (int k = 0; k < 4; ++k) row[4 * v + k] = a[k];
        }
#pragma unroll
        for (int q = 0; q < 4; ++q) {
#pragma unroll
            for (int c4 = 0; c4 < 4; ++c4) {
                f32x4 w;
#pragma unroll
                for (int k = 0; k < 4; ++k) {
                    int j = 4 * c4 + k;
                    w[k] = (j < 15) ? row[15 * q + j] : 0.f;
                }
                *(f32x4*)(xi2s + (size_t)r * 64 + q * 16 + c4 * 4) = w;
            }
        }
    }
}

// ---------------------------------------------------------------------------
// Gather with MFMA Wr: block = 1 wave, (combo, DG-dst CSR range).
// rW1/rb1 + rW2 frags in registers; segmented-scan scatter; 2 fences/tile.
// ---------------------------------------------------------------------------
template <int I, int F, int O, int C, int RANK>
__device__ __forceinline__ void gather_mfma(
    const int* __restrict__ offs,
    const float* __restrict__ rW1, const float* __restrict__ rb1,
    const unsigned short* __restrict__ bfH, const unsigned short* __restrict__ bfL,
    const float* __restrict__ cg,
    const float* __restrict__ eattr4, const float* __restrict__ xis,
    float* __restrict__ accO, int accStride,
    float* __restrict__ s_zbuf, float* __restrict__ s_wr, float* __restrict__ s_acc,
    int d0, int dGc, int estart, int eend) {
    constexpr int I2 = 2 * I + 1, F2 = 2 * F + 1, O2 = 2 * O + 1;
    constexpr int SA = 12 * O2;       // acc floats per dst
    constexpr int ZP = 68;            // zbuf row stride
    constexpr int WP = 148;           // s_wr row stride (144 cols + pad)
    constexpr int PQ = (I2 == 1) ? 4 : (I2 == 3) ? 12 : 16;   // floats per q-slice
    constexpr int PE = 4 * PQ;                                 // floats per edge
    const float inv = 0.28867513459481287f;  // 1/sqrt(12)
    const int lane = threadIdx.x;
    const int e = lane & 15;          // edge slot in tile
    const int q = lane >> 4;          // quarter 0..3

    for (int t = lane; t < DG * SA; t += GT) s_acc[t] = 0.f;
    LDS_FENCE();

    if (estart < eend) {
        // hoist rW2 fragments into registers
        bf16x8 wfH[9], wfL[9];
#pragma unroll
        for (int t9 = 0; t9 < 9; ++t9) {
            size_t boff = ((size_t)(C * 9 + t9) * 64 + lane) * 8;
            wfH[t9] = *(const bf16x8*)(bfH + boff);
            wfL[t9] = *(const bf16x8*)(bfL + boff);
        }
        // hoist rW1 slice + rb1 into registers (loop-invariant)
        float rw1r[10][8];
        float rb1r[8];
#pragma unroll
        for (int b = 0; b < 10; ++b)
#pragma unroll
            for (int j = 0; j < 8; ++j)
                rw1r[b][j] = rW1[(C * 10 + b) * 32 + 8 * q + j];
#pragma unroll
        for (int j = 0; j < 8; ++j) rb1r[j] = rb1[C * 32 + 8 * q + j];

        auto load_xi = [&](int rc, float (&xi)[3][I2]) {
            const f32x4* xp = (const f32x4*)(xis + (size_t)rc * PE + q * PQ);
            if constexpr (I2 == 1) {
                f32x4 v0 = xp[0];
                xi[0][0] = v0[0]; xi[1][0] = v0[1]; xi[2][0] = v0[2];
            } else if constexpr (I2 == 3) {
                f32x4 v0 = xp[0], v1 = xp[1], v2 = xp[2];
#pragma unroll
                for (int uu = 0; uu < 3; ++uu)
#pragma unroll
                    for (int a = 0; a < 3; ++a) {
                        int j = uu * 3 + a;
                        xi[uu][a] = (j < 4) ? v0[j] : (j < 8) ? v1[j - 4] : v2[j - 8];
                    }
            } else {
                f32x4 v0 = xp[0], v1 = xp[1], v2 = xp[2], v3 = xp[3];
#pragma unroll
                for (int uu = 0; uu < 3; ++uu)
#pragma unroll
                    for (int a = 0; a < 5; ++a) {
                        int j = uu * 5 + a;
                        xi[uu][a] = (j < 4) ? v0[j] : (j < 8) ? v1[j - 4]
                                  : (j < 12) ? v2[j - 8] : v3[j - 12];
                    }
            }
        };

        // ---- prime tile 0 ----
        int r0 = estart + e;
        bool valid = (r0 < eend);
        int rc = valid ? r0 : (eend - 1);
        f32x4 ea = *(const f32x4*)(eattr4 + (size_t)rc * 4);
        float xi[3][I2];
        load_xi(rc, xi);

        for (int tile = estart; tile < eend; tile += 16) {
            bool hasN = (tile + 16) < eend;
            int rN = tile + 16 + e;
            bool validN = (rN < eend);
            int rNc = validN ? rN : (eend - 1);

            int dst = __float_as_int(ea[3]);
            int local = dst - d0;
            float ex = ea[0], ey = ea[1], ez = ea[2];

            // segmented-scan masks for same-dst runs (elist is dst-sorted)
            int dstv = valid ? dst : (-1 - e);
            int du1 = __shfl_up(dstv, 1);
            int du2 = __shfl_up(dstv, 2);
            int du4 = __shfl_up(dstv, 4);
            int du8 = __shfl_up(dstv, 8);
            bool m1 = (e >= 1) && (du1 == dstv);
            bool m2 = (e >= 2) && (du2 == dstv);
            bool m4 = (e >= 4) && (du4 == dstv);
            bool m8 = (e >= 8) && (du8 == dstv);
            int dn = __shfl_down(dstv, 1);
            bool isEnd = (e == 15) || (dn != dstv);

            float d = sqrtf(ex * ex + ey * ey + ez * ez);
            float ri = 1.0f / fmaxf(d, 1e-9f);
            float x = ex * ri, y = ey * ri, zz = ez * ri;

            float rbf[10];
#pragma unroll
            for (int b = 0; b < 10; ++b) {
                float tt = d - 0.3888888888888889f * (float)b;
                rbf[b] = __expf(-4.0f * tt * tt);
            }

            // h slice (B-operand layout): pure register FMA
            bf16x8 hH, hL;
            {
#pragma unroll
                for (int j = 0; j < 8; ++j) {
                    float a = rb1r[j];
#pragma unroll
                    for (int b = 0; b < 10; ++b)
                        a = fmaf(rbf[b], rw1r[b][j], a);
                    a = fmaxf(a, 0.0f);
                    if (!valid) a = 0.0f;
                    unsigned short hi = bfhi(a);
                    hH[j] = (short)hi;
                    hL[j] = (short)bfhi(a - bff(hi));
                }
            }

            // prefetch next tile's eattr (linear address, in place)
            if (hasN) ea = *(const f32x4*)(eattr4 + (size_t)rNc * 4);

            // spherical harmonics (order F only)
            float Yf[F2];
            if constexpr (F == 0) {
                Yf[0] = 1.0f;
            } else if constexpr (F == 1) {
                const float s3 = 1.7320508075688772f;
                Yf[0] = s3 * y; Yf[1] = s3 * zz; Yf[2] = s3 * x;
            } else {
                const float s15 = 3.872983346207417f;
                const float s5 = 2.2360679774997896f;
                Yf[0] = s15 * x * y;
                Yf[1] = s15 * y * zz;
                Yf[2] = 0.5f * s5 * (3.0f * zz * zz - 1.0f);
                Yf[3] = s15 * x * zz;
                Yf[4] = 0.5f * s15 * (x * x - y * y);
            }

            // kY[a][oo] = sum_j CG[a,j,oo] * Yf[j]
            float kY[I2][O2];
#pragma unroll
            for (int a = 0; a < I2; ++a)
#pragma unroll
                for (int oo = 0; oo < O2; ++oo) {
                    float s = 0.f;
#pragma unroll
                    for (int j = 0; j < F2; ++j)
                        s = fmaf(cg[kCGOFF[C] + (a * F2 + j) * O2 + oo], Yf[j], s);
                    kY[a][oo] = s;
                }

            // z rows u = 3q..3q+2 from xi -> zbuf (last use of xi)
#pragma unroll
            for (int uu = 0; uu < 3; ++uu) {
                int u = 3 * q + uu;
#pragma unroll
                for (int oo = 0; oo < O2; ++oo) {
                    float s = 0.f;
#pragma unroll
                    for (int a = 0; a < I2; ++a) s = fmaf(xi[uu][a], kY[a][oo], s);
                    s_zbuf[e * ZP + u * O2 + oo] = s;
                }
            }

            // prefetch next tile's xi (linear address, in place)
            if (hasN) load_xi(rNc, xi);

            // MFMA phase: all 9 col-tiles, pure register inputs.
            // setprio: favor this wave while it occupies the matrix pipe
            // (independent 1-wave blocks at different phases share the SIMD).
            __builtin_amdgcn_s_setprio(1);
#pragma unroll
            for (int t9 = 0; t9 < 9; ++t9) {
                f32x4 a4 = {0.f, 0.f, 0.f, 0.f};
                a4 = __builtin_amdgcn_mfma_f32_16x16x32_bf16(wfH[t9], hH, a4, 0, 0, 0);
                a4 = __builtin_amdgcn_mfma_f32_16x16x32_bf16(wfL[t9], hH, a4, 0, 0, 0);
                a4 = __builtin_amdgcn_mfma_f32_16x16x32_bf16(wfH[t9], hL, a4, 0, 0, 0);
                // lane (e,q) holds Wr[e][16*t9 + 4q + rg] -> b128 store
                *(f32x4*)&s_wr[e * WP + 16 * t9 + 4 * q] = a4;
            }
            __builtin_amdgcn_s_setprio(0);
            LDS_FENCE();   // zbuf + s_wr visible

            // consumer: lane (e,q) -> edge e, v = 4g+q for g = 0..2
#pragma unroll
            for (int g = 0; g < 3; ++g) {
                f32x4 w0 = *(const f32x4*)&s_wr[e * WP + 48 * g + 12 * q + 0];
                f32x4 w1 = *(const f32x4*)&s_wr[e * WP + 48 * g + 12 * q + 4];
                f32x4 w2 = *(const f32x4*)&s_wr[e * WP + 48 * g + 12 * q + 8];

                float msg[O2];
#pragma unroll
                for (int oo = 0; oo < O2; ++oo) msg[oo] = 0.f;
#pragma unroll
                for (int u4 = 0; u4 < 4; ++u4) {
#pragma unroll
                    for (int oo = 0; oo < O2; ++oo) {
                        msg[oo] = fmaf(w0[u4], s_zbuf[e * ZP + u4 * O2 + oo], msg[oo]);
                        msg[oo] = fmaf(w1[u4], s_zbuf[e * ZP + (4 + u4) * O2 + oo], msg[oo]);
                        msg[oo] = fmaf(w2[u4], s_zbuf[e * ZP + (8 + u4) * O2 + oo], msg[oo]);
                    }
                }
#pragma unroll
                for (int oo = 0; oo < O2; ++oo) {
                    float v = msg[oo] * inv;
                    float t1 = __shfl_up(v, 1); if (m1) v += t1;
                    float t2 = __shfl_up(v, 2); if (m2) v += t2;
                    float t4 = __shfl_up(v, 4); if (m4) v += t4;
                    float t8 = __shfl_up(v, 8); if (m8) v += t8;
                    if (isEnd && valid)
                        unsafeAtomicAdd(&s_acc[local * SA + (4 * g + q) * O2 + oo], v);
                }
            }
            LDS_FENCE();   // WAR: next tile rewrites zbuf / s_wr

            valid = validN;
        }
    }

    LDS_FENCE();
    for (int t = lane; t < dGc * SA; t += GT) {
        int local = t / SA;
        int comp = t - local * SA;
        accO[(size_t)(d0 + local) * accStride + RANK * SA + comp] =
            s_acc[local * SA + comp];
    }
}

__global__ __launch_bounds__(GT) void gather_kernel(
    const int* __restrict__ offs,
    const float* __restrict__ rW1, const float* __restrict__ rb1,
    const unsigned short* __restrict__ bfH, const unsigned short* __restrict__ bfL,
    const float* __restrict__ cg,
    const float* __restrict__ eattr4,
    const float* __restrict__ xi0s, const float* __restrict__ xi1s,
    const float* __restrict__ xi2s,
    float* __restrict__ acc0, float* __restrict__ acc1, float* __restrict__ acc2,
    int Nn) {
    __shared__ __align__(16) float s_zbuf[16 * 68];
    __shared__ __align__(16) float s_wr[16 * 148];
    __shared__ __align__(16) float s_acc[DG * 60];
    int nb = (Nn + DG - 1) / DG;
    int cidx = blockIdx.x / nb;
    int dblk = blockIdx.x - cidx * nb;
    int combo = dCORDER[cidx];
    int d0 = dblk * DG;
    int dGc = Nn - d0;
    if (dGc > DG) dGc = DG;
    int estart = offs[d0];
    int eend = offs[d0 + dGc];

    switch (combo) {
    case 0:  gather_mfma<0,0,0, 0,0>(offs, rW1, rb1, bfH, bfL, cg, eattr4, xi0s, acc0,  36, s_zbuf, s_wr, s_acc, d0, dGc, estart, eend); break;
    case 1:  gather_mfma<0,1,1, 1,0>(offs, rW1, rb1, bfH, bfL, cg, eattr4, xi0s, acc1, 216, s_zbuf, s_wr, s_acc, d0, dGc, estart, eend); break;
    case 2:  gather_mfma<0,2,2, 2,0>(offs, rW1, rb1, bfH, bfL, cg, eattr4, xi0s, acc2, 360, s_zbuf, s_wr, s_acc, d0, dGc, estart, eend); break;
    case 3:  gather_mfma<1,0,1, 3,1>(offs, rW1, rb1, bfH, bfL, cg, eattr4, xi1s, acc1, 216, s_zbuf, s_wr, s_acc, d0, dGc, estart, eend); break;
    case 4:  gather_mfma<1,1,0, 4,1>(offs, rW1, rb1, bfH, bfL, cg, eattr4, xi1s, acc0,  36, s_zbuf, s_wr, s_acc, d0, dGc, estart, eend); break;
    case 5:  gather_mfma<1,1,1, 5,2>(offs, rW1, rb1, bfH, bfL, cg, eattr4, xi1s, acc1, 216, s_zbuf, s_wr, s_acc, d0, dGc, estart, eend); break;
    case 6:  gather_mfma<1,1,2, 6,1>(offs, rW1, rb1, bfH, bfL, cg, eattr4, xi1s, acc2, 360, s_zbuf, s_wr, s_acc, d0, dGc, estart, eend); break;
    case 7:  gather_mfma<1,2,1, 7,3>(offs, rW1, rb1, bfH, bfL, cg, eattr4, xi1s, acc1, 216, s_zbuf, s_wr, s_acc, d0, dGc, estart, eend); break;
    case 8:  gather_mfma<1,2,2, 8,2>(offs, rW1, rb1, bfH, bfL, cg, eattr4, xi1s, acc2, 360, s_zbuf, s_wr, s_acc, d0, dGc, estart, eend); break;
    case 9:  gather_mfma<2,0,2, 9,3>(offs, rW1, rb1, bfH, bfL, cg, eattr4, xi2s, acc2, 360, s_zbuf, s_wr, s_acc, d0, dGc, estart, eend); break;
    case 10: gather_mfma<2,1,1,10,4>(offs, rW1, rb1, bfH, bfL, cg, eattr4, xi2s, acc1, 216, s_zbuf, s_wr, s_acc, d0, dGc, estart, eend); break;
    case 11: gather_mfma<2,1,2,11,4>(offs, rW1, rb1, bfH, bfL, cg, eattr4, xi2s, acc2, 360, s_zbuf, s_wr, s_acc, d0, dGc, estart, eend); break;
    case 12: gather_mfma<2,2,0,12,2>(offs, rW1, rb1, bfH, bfL, cg, eattr4, xi2s, acc0,  36, s_zbuf, s_wr, s_acc, d0, dGc, estart, eend); break;
    case 13: gather_mfma<2,2,1,13,5>(offs, rW1, rb1, bfH, bfL, cg, eattr4, xi2s, acc1, 216, s_zbuf, s_wr, s_acc, d0, dGc, estart, eend); break;
    case 14: gather_mfma<2,2,2,14,5>(offs, rW1, rb1, bfH, bfL, cg, eattr4, xi2s, acc2, 360, s_zbuf, s_wr, s_acc, d0, dGc, estart, eend); break;
    }
}

// ---------------------------------------------------------------------------
// Output linears + activations: wave-per-node, LDS-staged acc row,
// lane-per-component, shuffle norms.
// ---------------------------------------------------------------------------
__global__ __launch_bounds__(256) void out_kernel(
    const float* __restrict__ acc0, const float* __restrict__ acc1,
    const float* __restrict__ acc2,
    const float* __restrict__ Wo0, const float* __restrict__ Wo1,
    const float* __restrict__ Wo2,
    float* __restrict__ out, int Nn) {
    __shared__ __align__(16) float s_a[4 * 612];
    const int wid = threadIdx.x >> 6;
    const int lane = threadIdx.x & 63;
    const int n = blockIdx.x * 4 + wid;
    if (n >= Nn) return;               // wave-uniform
    float* sa = s_a + wid * 612;

    // stage acc rows (612 floats) coalesced
    for (int t = lane; t < 153; t += 64) {
        f32x4 v;
        if (t < 9)       v = *(const f32x4*)(acc0 + (size_t)n * 36 + 4 * t);
        else if (t < 63) v = *(const f32x4*)(acc1 + (size_t)n * 216 + 4 * (t - 9));
        else             v = *(const f32x4*)(acc2 + (size_t)n * 360 + 4 * (t - 63));
        *(f32x4*)(sa + 4 * t) = v;
    }
    LDS_FENCE();   // wave-private slice

    // phase 0: o0, lanes 0-11 (v = lane)
    {
        int v = (lane < 12) ? lane : 0;
        float s = 0.f;
#pragma unroll
        for (int u = 0; u < 36; ++u) s = fmaf(Wo0[v * 36 + u], sa[u], s);
        s *= (1.0f / 6.0f);
        float r = s / (1.0f + __expf(-s));
        if (lane < 12) out[(size_t)n * 12 + v] = r;
    }
    // phase 1: o1, lanes 0-35 (v = l/3, m = l%3)
    {
        int l = (lane < 36) ? lane : 0;
        int v = l / 3, m = l - 3 * (l / 3);
        float y = 0.f;
#pragma unroll
        for (int u = 0; u < 72; ++u)
            y = fmaf(Wo1[v * 72 + u], sa[36 + u * 3 + m], y);
        y *= 0.11785113019775793f;  // 1/sqrt(72)
        int base = l - m;
        float y0 = __shfl(y, base + 0);
        float y1 = __shfl(y, base + 1);
        float y2 = __shfl(y, base + 2);
        float nr = sqrtf(y0 * y0 + y1 * y1 + y2 * y2);
        float g = (nr / (1.0f + __expf(-nr))) / fmaxf(nr, 1e-9f);
        if (lane < 36) out[(size_t)Nn * 12 + (size_t)n * 36 + v * 3 + m] = y * g;
    }
    // phase 2: o2, lanes 0-59 (v = l/5, m = l%5)
    {
        int l = (lane < 60) ? lane : 0;
        int v = l / 5, m = l - 5 * (l / 5);
        float y = 0.f;
#pragma unroll
        for (int u = 0; u < 72; ++u)
            y = fmaf(Wo2[v * 72 + u], sa[252 + u * 5 + m], y);
        y *= 0.11785113019775793f;  // 1/sqrt(72)
        int base = l - m;
        float nr2 = 0.f;
#pragma unroll
        for (int k = 0; k < 5; ++k) {
            float t = __shfl(y, base + k);
            nr2 = fmaf(t, t, nr2);
        }
        float nr = sqrtf(nr2);
        float g = (nr / (1.0f + __expf(-nr))) / fmaxf(nr, 1e-9f);
        if (lane < 60) out[(size_t)Nn * 48 + (size_t)n * 60 + v * 5 + m] = y * g;
    }
}

// ---------------------------------------------------------------------------
extern "C" void kernel_launch(void* const* d_in, const int* in_sizes, int n_in,
                              void* d_out, int out_size, void* d_ws, size_t ws_size,
                              hipStream_t stream) {
    const float* x0 = (const float*)d_in[0];
    const float* x1 = (const float*)d_in[1];
    const float* x2 = (const float*)d_in[2];
    const float* edge_attr = (const float*)d_in[3];
    const float* Wl0 = (const float*)d_in[4];
    const float* Wl1 = (const float*)d_in[5];
    const float* Wl2 = (const float*)d_in[6];
    const float* rW1 = (const float*)d_in[7];
    const float* rb1 = (const float*)d_in[8];
    const float* rW2 = (const float*)d_in[9];
    const float* Wo0 = (const float*)d_in[10];
    const float* Wo1 = (const float*)d_in[11];
    const float* Wo2 = (const float*)d_in[12];
    const int* eidx = (const int*)d_in[13];
    float* out = (float*)d_out;

    const int Nn = in_sizes[0] / 12;   // 10000
    const int Ee = in_sizes[3] / 3;    // 128000

    float* ws = (float*)d_ws;
    float* cg = ws;                                   // 640
    float* ins0 = ws + 640;                           // N*12
    float* ins1 = ins0 + (size_t)Nn * 12;             // N*36
    float* ins2 = ins1 + (size_t)Nn * 36;             // N*60
    float* acc0 = ins2 + (size_t)Nn * 60;             // N*36
    float* acc1 = acc0 + (size_t)Nn * 36;             // N*216
    float* acc2 = acc1 + (size_t)Nn * 216;            // N*360
    int* counts = (int*)(acc2 + (size_t)Nn * 360);    // N
    int* offs   = counts + Nn;                        // N+1
    int* cursor = offs + Nn + 1;                      // N
    int* elist  = cursor + Nn;                        // E
    size_t intEnd = (size_t)((char*)(elist + Ee) - (char*)d_ws);
    size_t bOff = (intEnd + 255) & ~(size_t)255;      // 16B-align bf16 frags
    unsigned short* bfH = (unsigned short*)((char*)d_ws + bOff);
    unsigned short* bfL = bfH + (size_t)NCOMB * 9 * 64 * 8;
    float* eattr4 = (float*)(bfL + (size_t)NCOMB * 9 * 64 * 8);
    float* xi0s = eattr4 + (size_t)Ee * 4;
    float* xi1s = xi0s + (size_t)Ee * 16;
    float* xi2s = xi1s + (size_t)Ee * 48;

    hipMemsetAsync(counts, 0, (size_t)Nn * sizeof(int), stream);

    cg_setup<<<NCOMB, 128, 0, stream>>>(cg);
    ins_kernel<<<(Nn + 255) / 256, 256, 0, stream>>>(x0, x1, x2, Wl0, Wl1, Wl2,
                                                     ins0, ins1, ins2, Nn);
    hist_kernel<<<(Ee + 255) / 256, 256, 0, stream>>>(eidx, counts, Ee);
    scan_kernel<<<1, 256, 0, stream>>>(counts, offs, cursor, Nn, Ee);
    fill_kernel<<<(Ee + 255) / 256, 256, 0, stream>>>(eidx, cursor, elist, Ee);
    bfrag_setup<<<NCOMB * 9, 64, 0, stream>>>(rW2, bfH, bfL);
    esort_kernel<<<(Ee + 255) / 256, 256, 0, stream>>>(eidx, elist, edge_attr,
                                                       ins0, ins1, ins2,
                                                       eattr4, xi0s, xi1s, xi2s, Ee);

    int nb = (Nn + DG - 1) / DG;
    gather_kernel<<<nb * NCOMB, GT, 0, stream>>>(offs, rW1, rb1, bfH, bfL, cg,
                                                 eattr4, xi0s, xi1s, xi2s,
                                                 acc0, acc1, acc2, Nn);

    out_kernel<<<(Nn + 3) / 4, 256, 0, stream>>>(acc0, acc1, acc2,
                                                 Wo0, Wo1, Wo2, out, Nn);
}

// Round 20
// 648.268 us; speedup vs baseline: 1.0323x; 1.0259x over previous
//
#include <hip/hip_runtime.h>
#include <math.h>

// ---------------------------------------------------------------------------
// E3NN conv: N=10000 nodes, E=128000 edges, MUL=12, B=10 rbf, H=32 hidden.
// 15 combos (i,f,o). Outputs: o0 (N,12), o1 (N,36), o2 (N,60) concat flat.
//
// Round 20: verified r18 single-tile base + geometry precompute ONLY.
// (r17 proved the r16/r17 corruption was the two-tile pipeline, NOT the geo
// stream — geo alone was never tested.) esort emits per-edge
// geo = [dst | rbf x10 | Y1 x3 | Y2 x5 | pad] (20 floats, 5 aligned f32x4);
// the gather drops sqrt/rcp/10x __expf/Yf (~200-400cy of transcendental
// dependency feeding the h-build) from every tile of all 15 passes.
// Everything else byte-identical to the verified r18 kernel.
// ---------------------------------------------------------------------------

#define NCOMB 15
#define DG 16          // dsts per block
#define GT 64          // gather block threads (1 wave)

// LDS visibility fence for single-wave LDS slices: no s_barrier, no vmcnt drain.
#define LDS_FENCE() do { \
    asm volatile("s_waitcnt lgkmcnt(0)" ::: "memory"); \
    __builtin_amdgcn_sched_barrier(0); \
} while (0)

typedef float f32x4 __attribute__((ext_vector_type(4)));
typedef short bf16x8 __attribute__((ext_vector_type(8)));

constexpr int kCGOFF[NCOMB] = {0,1,10,35,44,53,80,125,170,245,270,315,390,415,490};

__device__ const int dCI[NCOMB]    = {0,0,0,1,1,1,1,1,1,2,2,2,2,2,2};
__device__ const int dCF[NCOMB]    = {0,1,2,0,1,1,1,2,2,0,1,1,2,2,2};
__device__ const int dCO[NCOMB]    = {0,1,2,1,0,1,2,1,2,2,1,2,0,1,2};
__device__ const int dCGOFF[NCOMB] = {0,1,10,35,44,53,80,125,170,245,270,315,390,415,490};
// heavy combos (O2=5, big I2*F2) first -> short scheduling tail
__device__ const int dCORDER[NCOMB] = {14,8,11,2,9,6,13,7,10,5,12,3,1,4,0};

// bf16 round-to-nearest-even helpers
__device__ __forceinline__ unsigned short bfhi(float f) {
    unsigned u = __float_as_uint(f);
    return (unsigned short)((u + 0x7FFFu + ((u >> 16) & 1u)) >> 16);
}
__device__ __forceinline__ float bff(unsigned short h) {
    return __uint_as_float(((unsigned)h) << 16);
}

// ---------------------------------------------------------------------------
// CG setup (bit-matches numpy: contract-off, numpy's r2, lexicographic order)
// ---------------------------------------------------------------------------
__device__ inline double dfact(int n) {
    double r = 1.0;
    for (int k = 2; k <= n; ++k) r *= (double)k;
    return r;
}

__device__ double su2cg(int j1, int j2, int j3, int m1, int m2, int m3) {
#pragma clang fp contract(off)
    if (m1 + m2 != m3) return 0.0;
    double pref = sqrt((2.0 * j3 + 1.0) * dfact(j3 + j1 - j2) * dfact(j3 - j1 + j2) *
                       dfact(j1 + j2 - j3) / dfact(j1 + j2 + j3 + 1));
    pref *= sqrt(dfact(j3 + m3) * dfact(j3 - m3) * dfact(j1 - m1) * dfact(j1 + m1) *
                 dfact(j2 - m2) * dfact(j2 + m2));
    int k0 = 0;
    if (j2 - j3 - m1 > k0) k0 = j2 - j3 - m1;
    if (j1 - j3 + m2 > k0) k0 = j1 - j3 + m2;
    int k1 = j1 + j2 - j3;
    if (j1 - m1 < k1) k1 = j1 - m1;
    if (j2 + m2 < k1) k1 = j2 + m2;
    double s = 0.0;
    for (int k = k0; k <= k1; ++k) {
        double t = 1.0 / (dfact(k) * dfact(j1 + j2 - j3 - k) * dfact(j1 - m1 - k) *
                          dfact(j2 + m2 - k) * dfact(j3 - j2 + m1 + k) * dfact(j3 - j1 - m2 + k));
        s += (k & 1) ? -t : t;
    }
    return pref * s;
}

__device__ inline void qval(int l, int r, int c, double& re, double& im) {
#pragma clang fp contract(off)
    re = 0.0; im = 0.0;
    const double r2 = __longlong_as_double(0x3FE6A09E667F3BCCLL);  // numpy 1/sqrt(2)
    int m = r - l;
    if (m == 0) { if (c == l) re = 1.0; return; }
    if (m < 0) {
        if (c == r) im = -r2;
        else if (c == 2 * l - r) re = r2;
    } else {
        double sg = (m & 1) ? -1.0 : 1.0;
        if (c == r) re = sg * r2;
        else if (c == 2 * l - r) im = sg * r2;
    }
}

__global__ void cg_setup(float* __restrict__ out) {
#pragma clang fp contract(off)
    int c = blockIdx.x;
    if (c >= NCOMB) return;
    const int i = dCI[c], f = dCF[c], o = dCO[c];
    const int I2 = 2 * i + 1, F2 = 2 * f + 1, O2 = 2 * o + 1;
    const int sz = I2 * F2 * O2;
    const int t = threadIdx.x;

    double re = 0.0, im = 0.0;
    if (t < sz) {
        int a = t / (F2 * O2);
        int rem = t % (F2 * O2);
        int b = rem / O2;
        int cc = rem % O2;
        for (int ii = 0; ii < I2; ++ii) {
            double a1r, a1i; qval(i, a, ii, a1r, a1i);
            if (a1r == 0.0 && a1i == 0.0) continue;
            for (int jj = 0; jj < F2; ++jj) {
                double a2r, a2i; qval(f, b, jj, a2r, a2i);
                if (a2r == 0.0 && a2i == 0.0) continue;
                double pr = a1r * a2r - a1i * a2i;
                double pi = a1r * a2i + a1i * a2r;
                for (int kk = 0; kk < O2; ++kk) {
                    double C = su2cg(i, f, o, ii - i, jj - f, kk - o);
                    if (C == 0.0) continue;
                    double a3r, a3i; qval(o, cc, kk, a3r, a3i);
                    a3i = -a3i;
                    if (a3r == 0.0 && a3i == 0.0) continue;
                    double qr = pr * a3r - pi * a3i;
                    double qi = pr * a3i + pi * a3r;
                    re += qr * C;
                    im += qi * C;
                }
            }
        }
    }
    __shared__ double smre[128], smim[128];
    smre[t] = (t < sz) ? fabs(re) : 0.0;
    smim[t] = (t < sz) ? fabs(im) : 0.0;
    __syncthreads();
    __shared__ int useRe;
    if (t == 0) {
        double mr = 0.0, mi = 0.0;
        for (int k = 0; k < 128; ++k) {
            mr = fmax(mr, smre[k]);
            mi = fmax(mi, smim[k]);
        }
        useRe = (mr >= mi) ? 1 : 0;
    }
    __syncthreads();
    if (t < sz) out[dCGOFF[c] + t] = (float)(useRe ? re : im);
}

// ---------------------------------------------------------------------------
// Node input linears — row-vectorized (f32x4 loads/stores, static indices)
// ---------------------------------------------------------------------------
__global__ void ins_kernel(const float* __restrict__ x0, const float* __restrict__ x1,
                           const float* __restrict__ x2,
                           const float* __restrict__ Wl0, const float* __restrict__ Wl1,
                           const float* __restrict__ Wl2,
                           float* __restrict__ ins0, float* __restrict__ ins1,
                           float* __restrict__ ins2, int Nn) {
    int n = blockIdx.x * blockDim.x + threadIdx.x;
    if (n >= Nn) return;
    const float inv = 0.28867513459481287f;  // 1/sqrt(12)
    // l = 0
    {
        float xl[12];
#pragma unroll
        for (int k = 0; k < 3; ++k) {
            f32x4 v = *(const f32x4*)(x0 + (size_t)n * 12 + 4 * k);
#pragma unroll
            for (int j = 0; j < 4; ++j) xl[4 * k + j] = v[j];
        }
        float o[12];
#pragma unroll
        for (int v = 0; v < 12; ++v) {
            float s = 0.f;
#pragma unroll
            for (int u = 0; u < 12; ++u) s = fmaf(Wl0[v * 12 + u], xl[u], s);
            o[v] = s * inv;
        }
#pragma unroll
        for (int k = 0; k < 3; ++k) {
            f32x4 w = {o[4 * k], o[4 * k + 1], o[4 * k + 2], o[4 * k + 3]};
            *(f32x4*)(ins0 + (size_t)n * 12 + 4 * k) = w;
        }
    }
    // l = 1
    {
        float row[36];
#pragma unroll
        for (int k = 0; k < 9; ++k) {
            f32x4 v = *(const f32x4*)(x1 + (size_t)n * 36 + 4 * k);
#pragma unroll
            for (int j = 0; j < 4; ++j) row[4 * k + j] = v[j];
        }
        float o[36];
#pragma unroll
        for (int m = 0; m < 3; ++m)
#pragma unroll
            for (int v = 0; v < 12; ++v) {
                float s = 0.f;
#pragma unroll
                for (int u = 0; u < 12; ++u)
                    s = fmaf(Wl1[v * 12 + u], row[u * 3 + m], s);
                o[v * 3 + m] = s * inv;
            }
#pragma unroll
        for (int k = 0; k < 9; ++k) {
            f32x4 w = {o[4 * k], o[4 * k + 1], o[4 * k + 2], o[4 * k + 3]};
            *(f32x4*)(ins1 + (size_t)n * 36 + 4 * k) = w;
        }
    }
    // l = 2
    {
        float row[60];
#pragma unroll
        for (int k = 0; k < 15; ++k) {
            f32x4 v = *(const f32x4*)(x2 + (size_t)n * 60 + 4 * k);
#pragma unroll
            for (int j = 0; j < 4; ++j) row[4 * k + j] = v[j];
        }
        float o[60];
#pragma unroll
        for (int m = 0; m < 5; ++m)
#pragma unroll
            for (int v = 0; v < 12; ++v) {
                float s = 0.f;
#pragma unroll
                for (int u = 0; u < 12; ++u)
                    s = fmaf(Wl2[v * 12 + u], row[u * 5 + m], s);
                o[v * 5 + m] = s * inv;
            }
#pragma unroll
        for (int k = 0; k < 15; ++k) {
            f32x4 w = {o[4 * k], o[4 * k + 1], o[4 * k + 2], o[4 * k + 3]};
            *(f32x4*)(ins2 + (size_t)n * 60 + 4 * k) = w;
        }
    }
}

// ---------------------------------------------------------------------------
// CSR build: histogram -> exclusive scan -> cursor fill
// ---------------------------------------------------------------------------
__global__ void hist_kernel(const int* __restrict__ eidx, int* __restrict__ counts,
                            int Ee) {
    int e = blockIdx.x * blockDim.x + threadIdx.x;
    if (e >= Ee) return;
    atomicAdd(&counts[eidx[Ee + e]], 1);
}

__global__ void scan_kernel(const int* __restrict__ counts, int* __restrict__ offs,
                            int* __restrict__ cursor, int Nn, int Ee) {
    __shared__ int part[256];
    int t = threadIdx.x;
    const int CH = (Nn + 255) / 256;
    int base = t * CH;
    int s = 0;
    for (int k = 0; k < CH; ++k) {
        int i = base + k;
        if (i < Nn) s += counts[i];
    }
    part[t] = s;
    __syncthreads();
    for (int off = 1; off < 256; off <<= 1) {
        int v = (t >= off) ? part[t - off] : 0;
        __syncthreads();
        part[t] += v;
        __syncthreads();
    }
    int pre = (t == 0) ? 0 : part[t - 1];
    for (int k = 0; k < CH; ++k) {
        int i = base + k;
        if (i < Nn) {
            offs[i] = pre;
            cursor[i] = pre;
            pre += counts[i];
        }
    }
    if (t == 255) offs[Nn] = Ee;
}

__global__ void fill_kernel(const int* __restrict__ eidx, int* __restrict__ cursor,
                            int* __restrict__ elist, int Ee) {
    int e = blockIdx.x * blockDim.x + threadIdx.x;
    if (e >= Ee) return;
    int r = atomicAdd(&cursor[eidx[Ee + e]], 1);
    elist[r] = e;
}

// ---------------------------------------------------------------------------
// rW2 -> pre-swizzled bf16 hi/lo fragments (A operand of mfma(A=rW2tile,B=h)).
// Lane l of tile t holds rW2[k=8*(l>>4)+j][n=16*t+(l&15)], j=0..7.
// ---------------------------------------------------------------------------
__global__ void bfrag_setup(const float* __restrict__ rW2,
                            unsigned short* __restrict__ bfH,
                            unsigned short* __restrict__ bfL) {
    int blk = blockIdx.x;            // c*9 + t
    int c = blk / 9, t = blk % 9;
    int lane = threadIdx.x;
    int k0 = 8 * (lane >> 4);
    int n = 16 * t + (lane & 15);    // n = v*12+u in [0,144)
    size_t base = ((size_t)blk * 64 + lane) * 8;
#pragma unroll
    for (int j = 0; j < 8; ++j) {
        float val = rW2[(size_t)(c * 32 + k0 + j) * 144 + n];
        unsigned short hi = bfhi(val);
        bfH[base + j] = hi;
        bfL[base + j] = bfhi(val - bff(hi));
    }
}

// ---------------------------------------------------------------------------
// esort: permute edge data into CSR order + precompute geometry.
// geo[r] = [dstF | rbf0..9 | Y1_0..2 | Y2_0..4 | pad] (20 floats = 5 f32x4).
// xi streams in padded q-slice layout (unchanged from r18).
// ---------------------------------------------------------------------------
__global__ void esort_kernel(const int* __restrict__ eidx, const int* __restrict__ elist,
                             const float* __restrict__ edge_attr,
                             const float* __restrict__ ins0, const float* __restrict__ ins1,
                             const float* __restrict__ ins2,
                             float* __restrict__ geo,
                             float* __restrict__ xi0s, float* __restrict__ xi1s,
                             float* __restrict__ xi2s, int Ee) {
    int r = blockIdx.x * blockDim.x + threadIdx.x;
    if (r >= Ee) return;
    int e = elist[r];
    int src = eidx[e];
    int dst = eidx[Ee + e];
    float ex = edge_attr[3 * e + 0];
    float ey = edge_attr[3 * e + 1];
    float ez = edge_attr[3 * e + 2];
    float d = sqrtf(ex * ex + ey * ey + ez * ez);
    float ri = 1.0f / fmaxf(d, 1e-9f);
    float x = ex * ri, y = ey * ri, zz = ez * ri;

    float rbf[10];
#pragma unroll
    for (int b = 0; b < 10; ++b) {
        float tt = d - 0.3888888888888889f * (float)b;
        rbf[b] = __expf(-4.0f * tt * tt);
    }
    const float s3 = 1.7320508075688772f;
    const float s15 = 3.872983346207417f;
    const float s5 = 2.2360679774997896f;
    float Y1[3] = {s3 * y, s3 * zz, s3 * x};
    float Y2[5] = {s15 * x * y, s15 * y * zz, 0.5f * s5 * (3.0f * zz * zz - 1.0f),
                   s15 * x * zz, 0.5f * s15 * (x * x - y * y)};

    f32x4 g0 = {__int_as_float(dst), rbf[0], rbf[1], rbf[2]};
    f32x4 g1 = {rbf[3], rbf[4], rbf[5], rbf[6]};
    f32x4 g2 = {rbf[7], rbf[8], rbf[9], Y1[0]};
    f32x4 g3 = {Y1[1], Y1[2], Y2[0], Y2[1]};
    f32x4 g4 = {Y2[2], Y2[3], Y2[4], 0.f};
    f32x4* gp = (f32x4*)(geo + (size_t)r * 20);
    gp[0] = g0; gp[1] = g1; gp[2] = g2; gp[3] = g3; gp[4] = g4;

    {
        const f32x4* s = (const f32x4*)(ins0 + (size_t)src * 12);
        f32x4 a0 = s[0], a1 = s[1], a2 = s[2];
        float row[12];
#pragma unroll
        for (int k = 0; k < 4; ++k) { row[k] = a0[k]; row[4 + k] = a1[k]; row[8 + k] = a2[k]; }
#pragma unroll
        for (int q = 0; q < 4; ++q) {
            f32x4 w = {row[3 * q], row[3 * q + 1], row[3 * q + 2], 0.f};
            *(f32x4*)(xi0s + (size_t)r * 16 + q * 4) = w;
        }
    }
    {
        const f32x4* s = (const f32x4*)(ins1 + (size_t)src * 36);
        float row[36];
#pragma unroll
        for (int v = 0; v < 9; ++v) {
            f32x4 a = s[v];
#pragma unroll
            for (int k = 0; k < 4; ++k) row[4 * v + k] = a[k];
        }
#pragma unroll
        for (int q = 0; q < 4; ++q) {
#pragma unroll
            for (int c4 = 0; c4 < 3; ++c4) {
                f32x4 w;
#pragma unroll
                for (int k = 0; k < 4; ++k) {
                    int j = 4 * c4 + k;
                    w[k] = (j < 9) ? row[9 * q + j] : 0.f;
                }
                *(f32x4*)(xi1s + (size_t)r * 48 + q * 12 + c4 * 4) = w;
            }
        }
    }
    {
        const f32x4* s = (const f32x4*)(ins2 + (size_t)src * 60);
        float row[60];
#pragma unroll
        for (int v = 0; v < 15; ++v) {
            f32x4 a = s[v];
#pragma unroll
            for (int k = 0; k < 4; ++k) row[4 * v + k] = a[k];
        }
#pragma unroll
        for (int q = 0; q < 4; ++q) {
#pragma unroll
            for (int c4 = 0; c4 < 4; ++c4) {
                f32x4 w;
#pragma unroll
                for (int k = 0; k < 4; ++k) {
                    int j = 4 * c4 + k;
                    w[k] = (j < 15) ? row[15 * q + j] : 0.f;
                }
                *(f32x4*)(xi2s + (size_t)r * 64 + q * 16 + c4 * 4) = w;
            }
        }
    }
}

// ---------------------------------------------------------------------------
// Gather with MFMA Wr: block = 1 wave, (combo, DG-dst CSR range).
// Single-tile loop (verified structure); geometry read from geo stream.
// ---------------------------------------------------------------------------
template <int I, int F, int O, int C, int RANK>
__device__ __forceinline__ void gather_mfma(
    const int* __restrict__ offs,
    const float* __restrict__ rW1, const float* __restrict__ rb1,
    const unsigned short* __restrict__ bfH, const unsigned short* __restrict__ bfL,
    const float* __restrict__ cg,
    const float* __restrict__ geo, const float* __restrict__ xis,
    float* __restrict__ accO, int accStride,
    float* __restrict__ s_zbuf, float* __restrict__ s_wr, float* __restrict__ s_acc,
    int d0, int dGc, int estart, int eend) {
    constexpr int I2 = 2 * I + 1, F2 = 2 * F + 1, O2 = 2 * O + 1;
    constexpr int SA = 12 * O2;       // acc floats per dst
    constexpr int ZP = 68;            // zbuf row stride
    constexpr int WP = 148;           // s_wr row stride (144 cols + pad)
    constexpr int PQ = (I2 == 1) ? 4 : (I2 == 3) ? 12 : 16;   // floats per q-slice
    constexpr int PE = 4 * PQ;                                 // floats per edge
    const float inv = 0.28867513459481287f;  // 1/sqrt(12)
    const int lane = threadIdx.x;
    const int e = lane & 15;          // edge slot in tile
    const int q = lane >> 4;          // quarter 0..3

    for (int t = lane; t < DG * SA; t += GT) s_acc[t] = 0.f;
    LDS_FENCE();

    if (estart < eend) {
        // hoist rW2 fragments into registers
        bf16x8 wfH[9], wfL[9];
#pragma unroll
        for (int t9 = 0; t9 < 9; ++t9) {
            size_t boff = ((size_t)(C * 9 + t9) * 64 + lane) * 8;
            wfH[t9] = *(const bf16x8*)(bfH + boff);
            wfL[t9] = *(const bf16x8*)(bfL + boff);
        }
        // hoist rW1 slice + rb1 into registers (loop-invariant)
        float rw1r[10][8];
        float rb1r[8];
#pragma unroll
        for (int b = 0; b < 10; ++b)
#pragma unroll
            for (int j = 0; j < 8; ++j)
                rw1r[b][j] = rW1[(C * 10 + b) * 32 + 8 * q + j];
#pragma unroll
        for (int j = 0; j < 8; ++j) rb1r[j] = rb1[C * 32 + 8 * q + j];

        auto load_xi = [&](int rc, float (&xi)[3][I2]) {
            const f32x4* xp = (const f32x4*)(xis + (size_t)rc * PE + q * PQ);
            if constexpr (I2 == 1) {
                f32x4 v0 = xp[0];
                xi[0][0] = v0[0]; xi[1][0] = v0[1]; xi[2][0] = v0[2];
            } else if constexpr (I2 == 3) {
                f32x4 v0 = xp[0], v1 = xp[1], v2 = xp[2];
#pragma unroll
                for (int uu = 0; uu < 3; ++uu)
#pragma unroll
                    for (int a = 0; a < 3; ++a) {
                        int j = uu * 3 + a;
                        xi[uu][a] = (j < 4) ? v0[j] : (j < 8) ? v1[j - 4] : v2[j - 8];
                    }
            } else {
                f32x4 v0 = xp[0], v1 = xp[1], v2 = xp[2], v3 = xp[3];
#pragma unroll
                for (int uu = 0; uu < 3; ++uu)
#pragma unroll
                    for (int a = 0; a < 5; ++a) {
                        int j = uu * 5 + a;
                        xi[uu][a] = (j < 4) ? v0[j] : (j < 8) ? v1[j - 4]
                                  : (j < 12) ? v2[j - 8] : v3[j - 12];
                    }
            }
        };

        // ---- prime tile 0 ----
        int r0 = estart + e;
        bool valid = (r0 < eend);
        int rc = valid ? r0 : (eend - 1);
        f32x4 g0, g1, g2, g3, g4;
        {
            const f32x4* gp = (const f32x4*)(geo + (size_t)rc * 20);
            g0 = gp[0]; g1 = gp[1]; g2 = gp[2]; g3 = gp[3]; g4 = gp[4];
        }
        float xi[3][I2];
        load_xi(rc, xi);

        for (int tile = estart; tile < eend; tile += 16) {
            bool hasN = (tile + 16) < eend;
            int rN = tile + 16 + e;
            bool validN = (rN < eend);
            int rNc = validN ? rN : (eend - 1);

            int dst = __float_as_int(g0[0]);
            int local = dst - d0;

            // segmented-scan masks for same-dst runs (elist is dst-sorted)
            int dstv = valid ? dst : (-1 - e);
            int du1 = __shfl_up(dstv, 1);
            int du2 = __shfl_up(dstv, 2);
            int du4 = __shfl_up(dstv, 4);
            int du8 = __shfl_up(dstv, 8);
            bool m1 = (e >= 1) && (du1 == dstv);
            bool m2 = (e >= 2) && (du2 == dstv);
            bool m4 = (e >= 4) && (du4 == dstv);
            bool m8 = (e >= 8) && (du8 == dstv);
            int dn = __shfl_down(dstv, 1);
            bool isEnd = (e == 15) || (dn != dstv);

            // h slice (B-operand layout): pure register FMA from precomputed rbf
            // rbf[b] = b<3 ? g0[b+1] : b<7 ? g1[b-3] : g2[b-7]  (static indices)
            bf16x8 hH, hL;
            {
#pragma unroll
                for (int j = 0; j < 8; ++j) {
                    float a = rb1r[j];
#pragma unroll
                    for (int b = 0; b < 10; ++b) {
                        float rb = (b < 3) ? g0[b + 1] : (b < 7) ? g1[b - 3] : g2[b - 7];
                        a = fmaf(rb, rw1r[b][j], a);
                    }
                    a = fmaxf(a, 0.0f);
                    if (!valid) a = 0.0f;
                    unsigned short hi = bfhi(a);
                    hH[j] = (short)hi;
                    hL[j] = (short)bfhi(a - bff(hi));
                }
            }

            // spherical harmonics (order F only) from precomputed geo
            float Yf[F2];
            if constexpr (F == 0) {
                Yf[0] = 1.0f;
            } else if constexpr (F == 1) {
                Yf[0] = g2[3]; Yf[1] = g3[0]; Yf[2] = g3[1];
            } else {
                Yf[0] = g3[2]; Yf[1] = g3[3];
                Yf[2] = g4[0]; Yf[3] = g4[1]; Yf[4] = g4[2];
            }

            // kY[a][oo] = sum_j CG[a,j,oo] * Yf[j]
            float kY[I2][O2];
#pragma unroll
            for (int a = 0; a < I2; ++a)
#pragma unroll
                for (int oo = 0; oo < O2; ++oo) {
                    float s = 0.f;
#pragma unroll
                    for (int j = 0; j < F2; ++j)
                        s = fmaf(cg[kCGOFF[C] + (a * F2 + j) * O2 + oo], Yf[j], s);
                    kY[a][oo] = s;
                }

            // prefetch next tile's geo (linear addresses; g0..g4 fully consumed)
            if (hasN) {
                const f32x4* gp = (const f32x4*)(geo + (size_t)rNc * 20);
                g0 = gp[0]; g1 = gp[1]; g2 = gp[2]; g3 = gp[3]; g4 = gp[4];
            }

            // z rows u = 3q..3q+2 from xi -> zbuf (last use of xi)
#pragma unroll
            for (int uu = 0; uu < 3; ++uu) {
                int u = 3 * q + uu;
#pragma unroll
                for (int oo = 0; oo < O2; ++oo) {
                    float s = 0.f;
#pragma unroll
                    for (int a = 0; a < I2; ++a) s = fmaf(xi[uu][a], kY[a][oo], s);
                    s_zbuf[e * ZP + u * O2 + oo] = s;
                }
            }

            // prefetch next tile's xi (linear address, in place)
            if (hasN) load_xi(rNc, xi);

            // MFMA phase: all 9 col-tiles, pure register inputs
#pragma unroll
            for (int t9 = 0; t9 < 9; ++t9) {
                f32x4 a4 = {0.f, 0.f, 0.f, 0.f};
                a4 = __builtin_amdgcn_mfma_f32_16x16x32_bf16(wfH[t9], hH, a4, 0, 0, 0);
                a4 = __builtin_amdgcn_mfma_f32_16x16x32_bf16(wfL[t9], hH, a4, 0, 0, 0);
                a4 = __builtin_amdgcn_mfma_f32_16x16x32_bf16(wfH[t9], hL, a4, 0, 0, 0);
                // lane (e,q) holds Wr[e][16*t9 + 4q + rg] -> b128 store
                *(f32x4*)&s_wr[e * WP + 16 * t9 + 4 * q] = a4;
            }
            LDS_FENCE();   // zbuf + s_wr visible

            // consumer: lane (e,q) -> edge e, v = 4g+q for g = 0..2
#pragma unroll
            for (int g = 0; g < 3; ++g) {
                f32x4 w0 = *(const f32x4*)&s_wr[e * WP + 48 * g + 12 * q + 0];
                f32x4 w1 = *(const f32x4*)&s_wr[e * WP + 48 * g + 12 * q + 4];
                f32x4 w2 = *(const f32x4*)&s_wr[e * WP + 48 * g + 12 * q + 8];

                float msg[O2];
#pragma unroll
                for (int oo = 0; oo < O2; ++oo) msg[oo] = 0.f;
#pragma unroll
                for (int u4 = 0; u4 < 4; ++u4) {
#pragma unroll
                    for (int oo = 0; oo < O2; ++oo) {
                        msg[oo] = fmaf(w0[u4], s_zbuf[e * ZP + u4 * O2 + oo], msg[oo]);
                        msg[oo] = fmaf(w1[u4], s_zbuf[e * ZP + (4 + u4) * O2 + oo], msg[oo]);
                        msg[oo] = fmaf(w2[u4], s_zbuf[e * ZP + (8 + u4) * O2 + oo], msg[oo]);
                    }
                }
#pragma unroll
                for (int oo = 0; oo < O2; ++oo) {
                    float v = msg[oo] * inv;
                    float t1 = __shfl_up(v, 1); if (m1) v += t1;
                    float t2 = __shfl_up(v, 2); if (m2) v += t2;
                    float t4 = __shfl_up(v, 4); if (m4) v += t4;
                    float t8 = __shfl_up(v, 8); if (m8) v += t8;
                    if (isEnd && valid)
                        unsafeAtomicAdd(&s_acc[local * SA + (4 * g + q) * O2 + oo], v);
                }
            }
            LDS_FENCE();   // WAR: next tile rewrites zbuf / s_wr

            valid = validN;
        }
    }

    LDS_FENCE();
    for (int t = lane; t < dGc * SA; t += GT) {
        int local = t / SA;
        int comp = t - local * SA;
        accO[(size_t)(d0 + local) * accStride + RANK * SA + comp] =
            s_acc[local * SA + comp];
    }
}

__global__ __launch_bounds__(GT) void gather_kernel(
    const int* __restrict__ offs,
    const float* __restrict__ rW1, const float* __restrict__ rb1,
    const unsigned short* __restrict__ bfH, const unsigned short* __restrict__ bfL,
    const float* __restrict__ cg,
    const float* __restrict__ geo,
    const float* __restrict__ xi0s, const float* __restrict__ xi1s,
    const float* __restrict__ xi2s,
    float* __restrict__ acc0, float* __restrict__ acc1, float* __restrict__ acc2,
    int Nn) {
    __shared__ __align__(16) float s_zbuf[16 * 68];
    __shared__ __align__(16) float s_wr[16 * 148];
    __shared__ __align__(16) float s_acc[DG * 60];
    int nb = (Nn + DG - 1) / DG;
    int cidx = blockIdx.x / nb;
    int dblk = blockIdx.x - cidx * nb;
    int combo = dCORDER[cidx];
    int d0 = dblk * DG;
    int dGc = Nn - d0;
    if (dGc > DG) dGc = DG;
    int estart = offs[d0];
    int eend = offs[d0 + dGc];

    switch (combo) {
    case 0:  gather_mfma<0,0,0, 0,0>(offs, rW1, rb1, bfH, bfL, cg, geo, xi0s, acc0,  36, s_zbuf, s_wr, s_acc, d0, dGc, estart, eend); break;
    case 1:  gather_mfma<0,1,1, 1,0>(offs, rW1, rb1, bfH, bfL, cg, geo, xi0s, acc1, 216, s_zbuf, s_wr, s_acc, d0, dGc, estart, eend); break;
    case 2:  gather_mfma<0,2,2, 2,0>(offs, rW1, rb1, bfH, bfL, cg, geo, xi0s, acc2, 360, s_zbuf, s_wr, s_acc, d0, dGc, estart, eend); break;
    case 3:  gather_mfma<1,0,1, 3,1>(offs, rW1, rb1, bfH, bfL, cg, geo, xi1s, acc1, 216, s_zbuf, s_wr, s_acc, d0, dGc, estart, eend); break;
    case 4:  gather_mfma<1,1,0, 4,1>(offs, rW1, rb1, bfH, bfL, cg, geo, xi1s, acc0,  36, s_zbuf, s_wr, s_acc, d0, dGc, estart, eend); break;
    case 5:  gather_mfma<1,1,1, 5,2>(offs, rW1, rb1, bfH, bfL, cg, geo, xi1s, acc1, 216, s_zbuf, s_wr, s_acc, d0, dGc, estart, eend); break;
    case 6:  gather_mfma<1,1,2, 6,1>(offs, rW1, rb1, bfH, bfL, cg, geo, xi1s, acc2, 360, s_zbuf, s_wr, s_acc, d0, dGc, estart, eend); break;
    case 7:  gather_mfma<1,2,1, 7,3>(offs, rW1, rb1, bfH, bfL, cg, geo, xi1s, acc1, 216, s_zbuf, s_wr, s_acc, d0, dGc, estart, eend); break;
    case 8:  gather_mfma<1,2,2, 8,2>(offs, rW1, rb1, bfH, bfL, cg, geo, xi1s, acc2, 360, s_zbuf, s_wr, s_acc, d0, dGc, estart, eend); break;
    case 9:  gather_mfma<2,0,2, 9,3>(offs, rW1, rb1, bfH, bfL, cg, geo, xi2s, acc2, 360, s_zbuf, s_wr, s_acc, d0, dGc, estart, eend); break;
    case 10: gather_mfma<2,1,1,10,4>(offs, rW1, rb1, bfH, bfL, cg, geo, xi2s, acc1, 216, s_zbuf, s_wr, s_acc, d0, dGc, estart, eend); break;
    case 11: gather_mfma<2,1,2,11,4>(offs, rW1, rb1, bfH, bfL, cg, geo, xi2s, acc2, 360, s_zbuf, s_wr, s_acc, d0, dGc, estart, eend); break;
    case 12: gather_mfma<2,2,0,12,2>(offs, rW1, rb1, bfH, bfL, cg, geo, xi2s, acc0,  36, s_zbuf, s_wr, s_acc, d0, dGc, estart, eend); break;
    case 13: gather_mfma<2,2,1,13,5>(offs, rW1, rb1, bfH, bfL, cg, geo, xi2s, acc1, 216, s_zbuf, s_wr, s_acc, d0, dGc, estart, eend); break;
    case 14: gather_mfma<2,2,2,14,5>(offs, rW1, rb1, bfH, bfL, cg, geo, xi2s, acc2, 360, s_zbuf, s_wr, s_acc, d0, dGc, estart, eend); break;
    }
}

// ---------------------------------------------------------------------------
// Output linears + activations: wave-per-node, LDS-staged acc row,
// lane-per-component, shuffle norms.
// ---------------------------------------------------------------------------
__global__ __launch_bounds__(256) void out_kernel(
    const float* __restrict__ acc0, const float* __restrict__ acc1,
    const float* __restrict__ acc2,
    const float* __restrict__ Wo0, const float* __restrict__ Wo1,
    const float* __restrict__ Wo2,
    float* __restrict__ out, int Nn) {
    __shared__ __align__(16) float s_a[4 * 612];
    const int wid = threadIdx.x >> 6;
    const int lane = threadIdx.x & 63;
    const int n = blockIdx.x * 4 + wid;
    if (n >= Nn) return;               // wave-uniform
    float* sa = s_a + wid * 612;

    // stage acc rows (612 floats) coalesced
    for (int t = lane; t < 153; t += 64) {
        f32x4 v;
        if (t < 9)       v = *(const f32x4*)(acc0 + (size_t)n * 36 + 4 * t);
        else if (t < 63) v = *(const f32x4*)(acc1 + (size_t)n * 216 + 4 * (t - 9));
        else             v = *(const f32x4*)(acc2 + (size_t)n * 360 + 4 * (t - 63));
        *(f32x4*)(sa + 4 * t) = v;
    }
    LDS_FENCE();   // wave-private slice

    // phase 0: o0, lanes 0-11 (v = lane)
    {
        int v = (lane < 12) ? lane : 0;
        float s = 0.f;
#pragma unroll
        for (int u = 0; u < 36; ++u) s = fmaf(Wo0[v * 36 + u], sa[u], s);
        s *= (1.0f / 6.0f);
        float r = s / (1.0f + __expf(-s));
        if (lane < 12) out[(size_t)n * 12 + v] = r;
    }
    // phase 1: o1, lanes 0-35 (v = l/3, m = l%3)
    {
        int l = (lane < 36) ? lane : 0;
        int v = l / 3, m = l - 3 * (l / 3);
        float y = 0.f;
#pragma unroll
        for (int u = 0; u < 72; ++u)
            y = fmaf(Wo1[v * 72 + u], sa[36 + u * 3 + m], y);
        y *= 0.11785113019775793f;  // 1/sqrt(72)
        int base = l - m;
        float y0 = __shfl(y, base + 0);
        float y1 = __shfl(y, base + 1);
        float y2 = __shfl(y, base + 2);
        float nr = sqrtf(y0 * y0 + y1 * y1 + y2 * y2);
        float g = (nr / (1.0f + __expf(-nr))) / fmaxf(nr, 1e-9f);
        if (lane < 36) out[(size_t)Nn * 12 + (size_t)n * 36 + v * 3 + m] = y * g;
    }
    // phase 2: o2, lanes 0-59 (v = l/5, m = l%5)
    {
        int l = (lane < 60) ? lane : 0;
        int v = l / 5, m = l - 5 * (l / 5);
        float y = 0.f;
#pragma unroll
        for (int u = 0; u < 72; ++u)
            y = fmaf(Wo2[v * 72 + u], sa[252 + u * 5 + m], y);
        y *= 0.11785113019775793f;  // 1/sqrt(72)
        int base = l - m;
        float nr2 = 0.f;
#pragma unroll
        for (int k = 0; k < 5; ++k) {
            float t = __shfl(y, base + k);
            nr2 = fmaf(t, t, nr2);
        }
        float nr = sqrtf(nr2);
        float g = (nr / (1.0f + __expf(-nr))) / fmaxf(nr, 1e-9f);
        if (lane < 60) out[(size_t)Nn * 48 + (size_t)n * 60 + v * 5 + m] = y * g;
    }
}

// ---------------------------------------------------------------------------
extern "C" void kernel_launch(void* const* d_in, const int* in_sizes, int n_in,
                              void* d_out, int out_size, void* d_ws, size_t ws_size,
                              hipStream_t stream) {
    const float* x0 = (const float*)d_in[0];
    const float* x1 = (const float*)d_in[1];
    const float* x2 = (const float*)d_in[2];
    const float* edge_attr = (const float*)d_in[3];
    const float* Wl0 = (const float*)d_in[4];
    const float* Wl1 = (const float*)d_in[5];
    const float* Wl2 = (const float*)d_in[6];
    const float* rW1 = (const float*)d_in[7];
    const float* rb1 = (const float*)d_in[8];
    const float* rW2 = (const float*)d_in[9];
    const float* Wo0 = (const float*)d_in[10];
    const float* Wo1 = (const float*)d_in[11];
    const float* Wo2 = (const float*)d_in[12];
    const int* eidx = (const int*)d_in[13];
    float* out = (float*)d_out;

    const int Nn = in_sizes[0] / 12;   // 10000
    const int Ee = in_sizes[3] / 3;    // 128000

    float* ws = (float*)d_ws;
    float* cg = ws;                                   // 640
    float* ins0 = ws + 640;                           // N*12
    float* ins1 = ins0 + (size_t)Nn * 12;             // N*36
    float* ins2 = ins1 + (size_t)Nn * 36;             // N*60
    float* acc0 = ins2 + (size_t)Nn * 60;             // N*36
    float* acc1 = acc0 + (size_t)Nn * 36;             // N*216
    float* acc2 = acc1 + (size_t)Nn * 216;            // N*360
    int* counts = (int*)(acc2 + (size_t)Nn * 360);    // N
    int* offs   = counts + Nn;                        // N+1
    int* cursor = offs + Nn + 1;                      // N
    int* elist  = cursor + Nn;                        // E
    size_t intEnd = (size_t)((char*)(elist + Ee) - (char*)d_ws);
    size_t bOff = (intEnd + 255) & ~(size_t)255;      // 16B-align bf16 frags
    unsigned short* bfH = (unsigned short*)((char*)d_ws + bOff);
    unsigned short* bfL = bfH + (size_t)NCOMB * 9 * 64 * 8;
    float* geoB = (float*)(bfL + (size_t)NCOMB * 9 * 64 * 8);   // E*20
    float* xi0s = geoB + (size_t)Ee * 20;
    float* xi1s = xi0s + (size_t)Ee * 16;
    float* xi2s = xi1s + (size_t)Ee * 48;

    hipMemsetAsync(counts, 0, (size_t)Nn * sizeof(int), stream);

    cg_setup<<<NCOMB, 128, 0, stream>>>(cg);
    ins_kernel<<<(Nn + 255) / 256, 256, 0, stream>>>(x0, x1, x2, Wl0, Wl1, Wl2,
                                                     ins0, ins1, ins2, Nn);
    hist_kernel<<<(Ee + 255) / 256, 256, 0, stream>>>(eidx, counts, Ee);
    scan_kernel<<<1, 256, 0, stream>>>(counts, offs, cursor, Nn, Ee);
    fill_kernel<<<(Ee + 255) / 256, 256, 0, stream>>>(eidx, cursor, elist, Ee);
    bfrag_setup<<<NCOMB * 9, 64, 0, stream>>>(rW2, bfH, bfL);
    esort_kernel<<<(Ee + 255) / 256, 256, 0, stream>>>(eidx, elist, edge_attr,
                                                       ins0, ins1, ins2,
                                                       geoB, xi0s, xi1s, xi2s, Ee);

    int nb = (Nn + DG - 1) / DG;
    gather_kernel<<<nb * NCOMB, GT, 0, stream>>>(offs, rW1, rb1, bfH, bfL, cg,
                                                 geoB, xi0s, xi1s, xi2s,
                                                 acc0, acc1, acc2, Nn);

    out_kernel<<<(Nn + 3) / 4, 256, 0, stream>>>(acc0, acc1, acc2,
                                                 Wo0, Wo1, Wo2, out, Nn);
}